// Round 8
// baseline (7758.235 us; speedup 1.0000x reference)
//
#include <hip/hip_runtime.h>
#include <math.h>

// Problem constants
#define CB 16
#define CS 400
#define CT 51
#define CTM1 50
#define CV 50000
#define CE 128
#define CH 256
#define CMAXOOV 50
#define CEXT (CV + CMAXOOV)
#define CX 640             // E + H + H  (x = [emb|ctx|h])
#define NST 16             // state blocks
#define NWK 767            // vocab worker blocks
#define NBLK 784           // 16 state + 1 aggregator + 767 workers
#define NTILE 782          // ceil(V/64)
#define NR 64              // A-slab replicas

typedef __attribute__((ext_vector_type(4))) float f32x4;
typedef __attribute__((ext_vector_type(8))) short short8;
typedef unsigned int U32;
typedef unsigned long long U64;

__device__ __forceinline__ float wave_sum(float x) {
#pragma unroll
  for (int o = 32; o > 0; o >>= 1) x += __shfl_xor(x, o);
  return x;
}
__device__ __forceinline__ float sigm(float x) {
  return 1.f / (1.f + __expf(-x));
}
__device__ __forceinline__ float ftanh(float x) {
  x = fminf(fmaxf(x, -15.f), 15.f);
  float e = __expf(2.f * x);
  return (e - 1.f) / (e + 1.f);
}
__device__ __forceinline__ unsigned short f2bf(float f) {
  union { float f; U32 u; } x;
  x.f = f;
  U32 r = x.u + 0x7FFFu + ((x.u >> 16) & 1u);  // RNE
  return (unsigned short)(r >> 16);
}
__device__ __forceinline__ float bf2f(unsigned short u) {
  return __uint_as_float(((U32)u) << 16);
}
__device__ __forceinline__ U64 pack4(float a, float b, float c, float d) {
  return (U64)f2bf(a) | ((U64)f2bf(b) << 16) | ((U64)f2bf(c) << 32) |
         ((U64)f2bf(d) << 48);
}
// uncached (device-coherent) ops — tiny sync/exchange data only
__device__ __forceinline__ U32 ald32(const U32* p) {
  return __hip_atomic_load(p, __ATOMIC_RELAXED, __HIP_MEMORY_SCOPE_AGENT);
}
__device__ __forceinline__ U64 ald64(const U64* p) {
  return __hip_atomic_load(p, __ATOMIC_RELAXED, __HIP_MEMORY_SCOPE_AGENT);
}
__device__ __forceinline__ void ast32(U32* p, U32 v) {
  __hip_atomic_store(p, v, __ATOMIC_RELAXED, __HIP_MEMORY_SCOPE_AGENT);
}
__device__ __forceinline__ void ast64(U64* p, U64 v) {
  __hip_atomic_store(p, v, __ATOMIC_RELAXED, __HIP_MEMORY_SCOPE_AGENT);
}
#define VM0 asm volatile("s_waitcnt vmcnt(0)" ::: "memory")

// ---------------------------------------------------------------------------
// One-time weight prep
// ---------------------------------------------------------------------------
__global__ __launch_bounds__(256) void pw_convert(
    const float* __restrict__ W, unsigned short* __restrict__ Wb) {
  size_t i = ((size_t)blockIdx.x * 256 + threadIdx.x) * 8;
  float4 a = *(const float4*)(W + i);
  float4 b = *(const float4*)(W + i + 4);
  short8 o;
  o[0] = (short)f2bf(a.x); o[1] = (short)f2bf(a.y);
  o[2] = (short)f2bf(a.z); o[3] = (short)f2bf(a.w);
  o[4] = (short)f2bf(b.x); o[5] = (short)f2bf(b.y);
  o[6] = (short)f2bf(b.z); o[7] = (short)f2bf(b.w);
  *(short8*)(Wb + i) = o;
}

// WcatT[k][j] bf16: k<384 -> W_ih[j][k], else W_hh[j][k-384].  [640][1024]
__global__ __launch_bounds__(256) void pw_catT(
    const float* __restrict__ W_ih, const float* __restrict__ W_hh,
    unsigned short* __restrict__ WcatT) {
  int gid = blockIdx.x * 256 + threadIdx.x;  // 655,360
  int k = gid >> 10, j = gid & 1023;
  float v = (k < CE + CH) ? W_ih[(size_t)j * (CE + CH) + k]
                          : W_hh[(size_t)j * CH + (k - (CE + CH))];
  WcatT[gid] = f2bf(v);
}

// 256x256 fp32 transpose: out[j][k] = in[k][j]
__global__ __launch_bounds__(256) void pw_t256(const float* __restrict__ in,
                                               float* __restrict__ out) {
  int j = blockIdx.x, k = threadIdx.x;
  out[j * CH + k] = in[k * CH + j];
}

// ---------------------------------------------------------------------------
// P0: Wh_h16 (bf16) = enc @ W_h^T (coalesced via W_hT); copy_idx.
// ---------------------------------------------------------------------------
__global__ __launch_bounds__(256) void p0_precompute(
    const float* __restrict__ enc, const float* __restrict__ W_hT,
    const int* __restrict__ src_ids, const int* __restrict__ src_oov,
    unsigned short* __restrict__ Wh_h16, int* __restrict__ copy_idx) {
  const int row0 = blockIdx.x * 8, tid = threadIdx.x;
  __shared__ float erT[CH * 8];
#pragma unroll
  for (int i = 0; i < 8; ++i) {
    int idx = tid + i * 256;
    int r = idx >> 8, j = idx & 255;
    erT[j * 8 + r] = enc[(size_t)row0 * CH + idx];
  }
  if (tid < 8) {
    int row = row0 + tid;
    int ov = src_oov[row];
    copy_idx[row] = (ov >= 0) ? (CV + ov) : src_ids[row];
  }
  __syncthreads();
  float acc[8] = {0, 0, 0, 0, 0, 0, 0, 0};
#pragma unroll 4
  for (int j = 0; j < CH; ++j) {
    float w = W_hT[j * CH + tid];
    float4 e0 = *(const float4*)&erT[j * 8];
    float4 e1 = *(const float4*)&erT[j * 8 + 4];
    acc[0] += e0.x * w; acc[1] += e0.y * w; acc[2] += e0.z * w; acc[3] += e0.w * w;
    acc[4] += e1.x * w; acc[5] += e1.y * w; acc[6] += e1.z * w; acc[7] += e1.w * w;
  }
#pragma unroll
  for (int r = 0; r < 8; ++r)
    Wh_h16[(size_t)(row0 + r) * CH + tid] = f2bf(acc[r]);
}

// ---------------------------------------------------------------------------
// Z: zero control words + rowsum partials (every call: replay-safe).
// ctrl: arrive[16 slots, stride 16] @0 ; release[64 replicas, stride 16] @256
// ---------------------------------------------------------------------------
__global__ __launch_bounds__(256) void z_init(U32* __restrict__ ctrl,
                                              float* __restrict__ part) {
  int tid = blockIdx.x * 256 + threadIdx.x;
  if (tid < 2048) ctrl[tid] = 0u;
  for (int i = tid; i < CTM1 * CB * 64; i += 256 * 64) part[i] = 0.f;
}

// ---------------------------------------------------------------------------
// MEGA: 16 independent state blocks + 1 aggregator + 767 vocab workers.
// A-slab replicated x64 to avoid same-line UC read contention.
// ---------------------------------------------------------------------------
__global__ __launch_bounds__(256, 4) void mega(
    const int* __restrict__ tgt, const float* __restrict__ hidden,
    const float* __restrict__ cell, const float* __restrict__ enc,
    const int* __restrict__ src_lens, const float* __restrict__ embedding,
    const float* __restrict__ w_c, const float* __restrict__ v_vec,
    const float* __restrict__ b_attn, const float* __restrict__ b_ih,
    const float* __restrict__ b_hh, const float* __restrict__ W_pg,
    const float* __restrict__ b_pg, const float* __restrict__ b_out,
    const unsigned short* __restrict__ Wh_h16, const float* __restrict__ W_sT,
    const unsigned short* __restrict__ WcatT,
    const unsigned short* __restrict__ Wb, U64* __restrict__ A64R,
    unsigned short* __restrict__ attn16, float* __restrict__ p_gen_g,
    float* __restrict__ part, float* __restrict__ covloss_b,
    U32* __restrict__ ctrl, float* __restrict__ dout) {
  const int bid = blockIdx.x, tid = threadIdx.x;
  const int lane = tid & 63, wv = tid >> 6;
  U32* arrive = ctrl;          // 16 slots, stride 16
  U32* release = ctrl + 256;   // 64 replicas, stride 16

  __shared__ __align__(16) U64 sh_big[2080];  // vocab: A LDS / state: a_pack
  __shared__ float cov_s[CS];
  __shared__ float a_s[CS];
  __shared__ __align__(16) float h_cur[CH];
  __shared__ float hws_s[CH];
  __shared__ __align__(16) float ctx_s[CH];
  __shared__ float x_f[CX];
  __shared__ float g_sh[4 * CH];
  __shared__ float red[4];
  __shared__ float stat[4];
  __shared__ float prs[4][16];
  __shared__ float rsum_loc[16];

  if (bid < NST) {
    // ============== STATE LANE (batch b) — no cross-block waits ==========
    const int b = bid;
    const int len = src_lens[b];
    const float ba = b_attn[0];
    const int k4 = lane * 4;
    const float4 wc4 = *(const float4*)(w_c + k4);
    const float4 vv4 = *(const float4*)(v_vec + k4);
    float bias0 = b_ih[tid * 4] + b_hh[tid * 4];
    float bias1 = b_ih[tid * 4 + 1] + b_hh[tid * 4 + 1];
    float bias2 = b_ih[tid * 4 + 2] + b_hh[tid * 4 + 2];
    float bias3 = b_ih[tid * 4 + 3] + b_hh[tid * 4 + 3];
    float covl = 0.f;
    float c_reg = cell[b * CH + tid];
    U64* a_pack = sh_big;  // [128] u64 = packed A row

    for (int i = tid; i < CS; i += 256) cov_s[i] = 0.f;
    h_cur[tid] = hidden[b * CH + tid];
    __syncthreads();
    {
      float acc = 0.f;
#pragma unroll 8
      for (int j = 0; j < CH; ++j) acc += h_cur[j] * W_sT[j * CH + tid];
      hws_s[tid] = acc;
    }
    __syncthreads();

    for (int t = 0; t < CTM1; ++t) {
      // -- coverage update + covloss(t-1)
      if (t > 0) {
        for (int s = tid; s < CS; s += 256) {
          float a = a_s[s], cv = cov_s[s];
          covl += fminf(a, cv);
          cov_s[s] = cv + a;
        }
        __syncthreads();
      }
      // -- scores (no-max exp): wave per s, lanes over k (bf16 Wh_h)
      float ps = 0.f;
      for (int s = wv; s < CS; s += 4) {
        float cv = cov_s[s];
        U64 wq = *(const U64*)(Wh_h16 + ((size_t)(b * CS + s)) * CH + k4);
        float p =
            ftanh(bf2f((unsigned short)wq) + hws_s[k4] + cv * wc4.x + ba) *
                vv4.x +
            ftanh(bf2f((unsigned short)(wq >> 16)) + hws_s[k4 + 1] +
                  cv * wc4.y + ba) *
                vv4.y +
            ftanh(bf2f((unsigned short)(wq >> 32)) + hws_s[k4 + 2] +
                  cv * wc4.z + ba) *
                vv4.z +
            ftanh(bf2f((unsigned short)(wq >> 48)) + hws_s[k4 + 3] +
                  cv * wc4.w + ba) *
                vv4.w;
        p = wave_sum(p);
        if (lane == 0) {
          float e = (s < len) ? __expf(p) : 0.f;  // |score| <~ 10: safe
          a_s[s] = e;
          ps += e;
        }
      }
      if (lane == 0) red[wv] = ps;
      __syncthreads();
      if (tid == 0) stat[0] = 1.f / (red[0] + red[1] + red[2] + red[3]);
      __syncthreads();
      const float inv = stat[0];
      for (int s = tid; s < CS; s += 256) {
        float a = a_s[s] * inv;
        a_s[s] = a;
        attn16[((size_t)t * CB + b) * CS + s] = f2bf(a);
      }
      __syncthreads();
      // -- context (thread owns k=tid), x assembly
      {
        float pc = 0.f;
        const float* er = enc + ((size_t)b * CS) * CH + tid;
#pragma unroll 16
        for (int s = 0; s < CS; ++s) pc += a_s[s] * er[(size_t)s * CH];
        ctx_s[tid] = pc;
        x_f[CE + tid] = pc;
        x_f[CE + CH + tid] = h_cur[tid];
      }
      const int tok = tgt[b * CT + t];
      float emb_v = 0.f;
      if (tid < CE) {
        emb_v = embedding[(size_t)tok * CE + tid];
        x_f[tid] = emb_v;
      }
      __syncthreads();
      // -- gates (batch-local GEMV, bf16 WcatT stream): cols tid*4..+3
      {
        float a0 = 0.f, a1 = 0.f, a2 = 0.f, a3 = 0.f;
        const U64* wt = (const U64*)WcatT;
#pragma unroll 4
        for (int k = 0; k < CX; ++k) {
          U64 w = wt[(size_t)k * 256 + tid];
          float xk = x_f[k];
          a0 += xk * bf2f((unsigned short)w);
          a1 += xk * bf2f((unsigned short)(w >> 16));
          a2 += xk * bf2f((unsigned short)(w >> 32));
          a3 += xk * bf2f((unsigned short)(w >> 48));
        }
        g_sh[tid * 4] = a0 + bias0;
        g_sh[tid * 4 + 1] = a1 + bias1;
        g_sh[tid * 4 + 2] = a2 + bias2;
        g_sh[tid * 4 + 3] = a3 + bias3;
      }
      __syncthreads();
      // -- cell update (thread owns unit u=tid)
      float hn;
      {
        float gi = g_sh[tid], gf = g_sh[CH + tid];
        float gg2 = g_sh[2 * CH + tid], go = g_sh[3 * CH + tid];
        float cn = sigm(gf) * c_reg + sigm(gi) * ftanh(gg2);
        c_reg = cn;
        hn = sigm(go) * ftanh(cn);
        h_cur[tid] = hn;
      }
      __syncthreads();
      // -- pack A row [h|ctx] bf16 into LDS, then replicate to NR copies
      if (tid < 64)
        a_pack[tid] = pack4(h_cur[4 * tid], h_cur[4 * tid + 1],
                            h_cur[4 * tid + 2], h_cur[4 * tid + 3]);
      else if (tid < 128) {
        int i = tid - 64;
        a_pack[64 + i] = pack4(ctx_s[4 * i], ctx_s[4 * i + 1],
                               ctx_s[4 * i + 2], ctx_s[4 * i + 3]);
      }
      __syncthreads();
      {
        U64* dst = A64R + (size_t)t * (NR * 2048) + b * 128;
#pragma unroll
        for (int q = 0; q < 32; ++q) {
          int idx = q * 256 + tid;  // 0..8191 = rep*128 + i
          int rep = idx >> 7, i = idx & 127;
          ast64(dst + (size_t)rep * 2048 + i, a_pack[i]);
        }
      }
      VM0;
      if (tid == 0) ast32(&arrive[b * 16], (U32)(t + 1));
      // -- off-critical-path: hWs(next) + p_gen
      {
        float acc = 0.f;
#pragma unroll 8
        for (int j = 0; j < CH; ++j) acc += h_cur[j] * W_sT[j * CH + tid];
        hws_s[tid] = acc;
      }
      {
        float z = hn * W_pg[tid] + ctx_s[tid] * W_pg[CH + tid];
        if (tid < CE) z += emb_v * W_pg[2 * CH + tid];
        z = wave_sum(z);
        if (lane == 0) red[wv] = z;
        __syncthreads();
        if (tid == 0)
          p_gen_g[t * CB + b] =
              sigm(red[0] + red[1] + red[2] + red[3] + b_pg[0]);
      }
      __syncthreads();
    }
    // tail: covloss t=49 term, totals, hT/cT straight into dout
    for (int s = tid; s < CS; s += 256) covl += fminf(a_s[s], cov_s[s]);
    covl = wave_sum(covl);
    if (lane == 0) red[wv] = covl;
    __syncthreads();
    if (tid == 0) covloss_b[b] = red[0] + red[1] + red[2] + red[3];
    const size_t D0 = (size_t)CB * CTM1 * CEXT;
    dout[D0 + b * CH + tid] = h_cur[tid];
    dout[D0 + CB * CH + b * CH + tid] = c_reg;
  } else if (bid == NST) {
    // ===================== AGGREGATOR (1 block) ==========================
    for (int t = 0; t < CTM1; ++t) {
      if (wv == 0) {
        int gg = 0;
        while (gg < (1 << 20)) {
          U32 v = (lane < NST) ? ald32(&arrive[lane * 16]) : (U32)(t + 1);
          if (__all(v >= (U32)(t + 1))) break;
          __builtin_amdgcn_s_sleep(8);
          ++gg;
        }
      }
      __syncthreads();
      if (tid < 64) ast32(&release[tid * 16], (U32)(t + 1));
      __syncthreads();
    }
  } else {
    // ===================== VOCAB WORKERS (767 blocks) ====================
    const int vb = bid - NST - 1;
    const int rep = vb & 63;
    const int nn = lane & 15, g = lane >> 4;
    U64* a64l = sh_big;  // [16][130] u64 (65-short8 row stride)
    const short8* lds8 = (const short8*)sh_big;
    for (int t = 0; t < CTM1; ++t) {
      if (tid == 0) {  // poll own replica line
        int gg = 0;
        while (ald32(&release[rep * 16]) < (U32)(t + 1) && ++gg < (1 << 18))
          __builtin_amdgcn_s_sleep(64);
      }
      __syncthreads();
      {  // stage own A replica (UC) -> LDS
        const U64* src = A64R + (size_t)t * (NR * 2048) + (size_t)rep * 2048;
#pragma unroll
        for (int i = 0; i < 8; ++i) {
          int idx = tid + i * 256;
          int row = idx >> 7, col = idx & 127;
          a64l[row * 130 + col] = ald64(&src[idx]);
        }
      }
      if (tid < 16) rsum_loc[tid] = 0.f;
      __syncthreads();
      short8 af[16];
#pragma unroll
      for (int kt = 0; kt < 16; ++kt) af[kt] = lds8[nn * 65 + kt * 4 + g];
      for (int tile = vb; tile < NTILE; tile += NWK) {
        int v = tile * 64 + wv * 16 + nn;
        bool ok = v < CV;
        int vc = ok ? v : CV - 1;
        const short8* bp = (const short8*)Wb + (size_t)vc * 64;  // cached
        f32x4 acc = {0.f, 0.f, 0.f, 0.f};
#pragma unroll
        for (int kt = 0; kt < 16; ++kt)
          acc = __builtin_amdgcn_mfma_f32_16x16x32_bf16(af[kt], bp[kt * 4 + g],
                                                        acc, 0, 0, 0);
        float bo = ok ? b_out[v] : 0.f;
        float ev[4];
#pragma unroll
        for (int r = 0; r < 4; ++r) {
          float e = ok ? __expf(acc[r] + bo) : 0.f;
          if (ok) dout[((size_t)((g * 4 + r) * CTM1 + t)) * CEXT + v] = e;
#pragma unroll
          for (int o = 1; o < 16; o <<= 1) e += __shfl_xor(e, o);
          ev[r] = e;
        }
        if (nn == 0) {
#pragma unroll
          for (int r = 0; r < 4; ++r) prs[wv][g * 4 + r] = ev[r];
        }
        __syncthreads();
        if (tid < 16)
          rsum_loc[tid] +=
              prs[0][tid] + prs[1][tid] + prs[2][tid] + prs[3][tid];
        __syncthreads();
      }
      if (tid < 16)
        atomicAdd(&part[((size_t)t * CB + tid) * 64 + rep], rsum_loc[tid]);
    }
  }
}

// ---------------------------------------------------------------------------
// POST 1: per (b,t) row: reduce 64 rowsum partials, normalize + zero pads.
// ---------------------------------------------------------------------------
__global__ __launch_bounds__(256) void post_norm(
    const float* __restrict__ part, const float* __restrict__ p_gen_g,
    float* __restrict__ dout) {
  const int R = blockIdx.x;
  const int b = R / CTM1, t = R % CTM1;
  const int tid = threadIdx.x;
  __shared__ float stat;
  float s = (tid < 64) ? part[((size_t)t * CB + b) * 64 + tid] : 0.f;
  s = wave_sum(s);
  if (tid == 0) stat = p_gen_g[t * CB + b] / s;
  __syncthreads();
  float inv = stat;
  float* drow = dout + (size_t)R * CEXT;
  for (int v = tid; v < CEXT; v += 256)
    drow[v] = (v < CV) ? drow[v] * inv : 0.f;
}

// ---------------------------------------------------------------------------
// POST 2: copy-dist scatter for all t + coverage_loss. grid = 16.
// ---------------------------------------------------------------------------
__global__ __launch_bounds__(256) void post_tail(
    const unsigned short* __restrict__ attn16,
    const float* __restrict__ p_gen_g, const int* __restrict__ copy_idx,
    const float* __restrict__ covloss_b, float* __restrict__ dout) {
  const int b = blockIdx.x, tid = threadIdx.x;
  for (int t = 0; t < CTM1; ++t) {
    float pg1 = 1.f - p_gen_g[t * CB + b];
    const unsigned short* ar = attn16 + ((size_t)t * CB + b) * CS;
    float* drow = dout + ((size_t)(b * CTM1 + t)) * CEXT;
    for (int s = tid; s < CS; s += 256)
      atomicAdd(drow + copy_idx[b * CS + s], pg1 * bf2f(ar[s]));
  }
  if (b == 0 && tid == 0) {
    const size_t D0 = (size_t)CB * CTM1 * CEXT;
    float s = 0.f;
    for (int i = 0; i < CB; ++i) s += covloss_b[i];
    dout[D0 + 2 * CB * CH] = s / (float)(CTM1 * CB);
  }
}

// ---------------------------------------------------------------------------
extern "C" void kernel_launch(void* const* d_in, const int* in_sizes, int n_in,
                              void* d_out, int out_size, void* d_ws,
                              size_t ws_size, hipStream_t stream) {
  const int* tgt = (const int*)d_in[0];
  const float* hidden = (const float*)d_in[1];
  const float* cell = (const float*)d_in[2];
  const float* enc = (const float*)d_in[3];
  const int* src_lens = (const int*)d_in[4];
  const int* src_ids = (const int*)d_in[5];
  const int* src_oov = (const int*)d_in[6];
  const float* embedding = (const float*)d_in[7];
  const float* W_h = (const float*)d_in[8];
  const float* W_s = (const float*)d_in[9];
  const float* w_c = (const float*)d_in[10];
  const float* v_vec = (const float*)d_in[11];
  const float* b_attn = (const float*)d_in[12];
  const float* W_ih = (const float*)d_in[13];
  const float* W_hh = (const float*)d_in[14];
  const float* b_ih = (const float*)d_in[15];
  const float* b_hh = (const float*)d_in[16];
  const float* W_pg = (const float*)d_in[17];
  const float* b_pg = (const float*)d_in[18];
  const float* W_out = (const float*)d_in[19];
  const float* b_out = (const float*)d_in[20];
  float* dout = (float*)d_out;

  // workspace layout (A64R 8B-aligned: word count before it is even)
  float* ws = (float*)d_ws;
  float* W_sT = ws;                                  // 65,536 f
  float* W_hT = W_sT + CH * CH;                      // 65,536 f
  float* p_gen_g = W_hT + CH * CH;                   // 800 f
  float* part = p_gen_g + CTM1 * CB;                 // 51,200 f
  float* covloss_b = part + CTM1 * CB * 64;          // 16 f
  int* copy_idx = (int*)(covloss_b + 16);            // 6,400 i
  U32* ctrl = (U32*)(copy_idx + CB * CS);            // 2,048 u32
  U64* A64R = (U64*)(ctrl + 2048);                   // 50*64*2048 u64 (52 MB)
  unsigned short* attn16 =
      (unsigned short*)(A64R + (size_t)CTM1 * NR * 2048);       // 320,000 sh
  unsigned short* Wh_h16 = attn16 + (size_t)CTM1 * CB * CS;     // 1,638,400 sh
  unsigned short* WcatT = Wh_h16 + (size_t)CB * CS * CH;        // 655,360 sh
  unsigned short* Wb = WcatT + (size_t)CX * 1024;    // 25,600,000 sh

  z_init<<<64, 256, 0, stream>>>(ctrl, part);
  pw_convert<<<(CV * 2 * CH) / (256 * 8), 256, 0, stream>>>(W_out, Wb);
  pw_catT<<<(CX * 1024) / 256, 256, 0, stream>>>(W_ih, W_hh, WcatT);
  pw_t256<<<CH, CH, 0, stream>>>(W_s, W_sT);
  pw_t256<<<CH, CH, 0, stream>>>(W_h, W_hT);
  p0_precompute<<<CB * CS / 8, 256, 0, stream>>>(enc, W_hT, src_ids, src_oov,
                                                 Wh_h16, copy_idx);

  void* kargs[] = {
      (void*)&tgt,      (void*)&hidden,    (void*)&cell,     (void*)&enc,
      (void*)&src_lens, (void*)&embedding, (void*)&w_c,      (void*)&v_vec,
      (void*)&b_attn,   (void*)&b_ih,      (void*)&b_hh,     (void*)&W_pg,
      (void*)&b_pg,     (void*)&b_out,     (void*)&Wh_h16,   (void*)&W_sT,
      (void*)&WcatT,    (void*)&Wb,        (void*)&A64R,     (void*)&attn16,
      (void*)&p_gen_g,  (void*)&part,      (void*)&covloss_b,(void*)&ctrl,
      (void*)&dout};
  hipError_t e = hipLaunchCooperativeKernel((const void*)mega, dim3(NBLK),
                                            dim3(256), kargs, 0, stream);
  if (e != hipSuccess) {
    hipLaunchKernelGGL(mega, dim3(NBLK), dim3(256), 0, stream, tgt, hidden,
                       cell, enc, src_lens, embedding, w_c, v_vec, b_attn,
                       b_ih, b_hh, W_pg, b_pg, b_out, Wh_h16, W_sT, WcatT, Wb,
                       A64R, attn16, p_gen_g, part, covloss_b, ctrl, dout);
  }
  post_norm<<<CB * CTM1, 256, 0, stream>>>(part, p_gen_g, dout);
  post_tail<<<CB, 256, 0, stream>>>(attn16, p_gen_g, copy_idx, covloss_b,
                                    dout);
}

// Round 9
// 7716.567 us; speedup vs baseline: 1.0054x; 1.0054x over previous
//
#include <hip/hip_runtime.h>
#include <math.h>

// Problem constants
#define CB 16
#define CS 400
#define CT 51
#define CTM1 50
#define CV 50000
#define CE 128
#define CH 256
#define CMAXOOV 50
#define CEXT (CV + CMAXOOV)
#define CX 640             // E + H + H  (x = [emb|ctx|h])
#define NST 16             // state blocks
#define NWK 767            // vocab worker blocks
#define NBLK 784           // 16 state + 1 aggregator + 767 workers
#define NTILE 782          // ceil(V/64)

typedef __attribute__((ext_vector_type(4))) float f32x4;
typedef __attribute__((ext_vector_type(8))) short short8;
typedef unsigned int U32;
typedef unsigned long long U64;

__device__ __forceinline__ float wave_sum(float x) {
#pragma unroll
  for (int o = 32; o > 0; o >>= 1) x += __shfl_xor(x, o);
  return x;
}
__device__ __forceinline__ float sigm(float x) {
  return 1.f / (1.f + __expf(-x));
}
__device__ __forceinline__ float ftanh(float x) {
  x = fminf(fmaxf(x, -15.f), 15.f);
  float e = __expf(2.f * x);
  return (e - 1.f) / (e + 1.f);
}
__device__ __forceinline__ unsigned short f2bf(float f) {
  union { float f; U32 u; } x;
  x.f = f;
  U32 r = x.u + 0x7FFFu + ((x.u >> 16) & 1u);  // RNE
  return (unsigned short)(r >> 16);
}
__device__ __forceinline__ float bf2f(unsigned short u) {
  return __uint_as_float(((U32)u) << 16);
}
__device__ __forceinline__ U64 pack4(float a, float b, float c, float d) {
  return (U64)f2bf(a) | ((U64)f2bf(b) << 16) | ((U64)f2bf(c) << 32) |
         ((U64)f2bf(d) << 48);
}
// uncached (device-coherent) ops — flags + producer-side publishes ONLY
__device__ __forceinline__ U32 ald32(const U32* p) {
  return __hip_atomic_load(p, __ATOMIC_RELAXED, __HIP_MEMORY_SCOPE_AGENT);
}
__device__ __forceinline__ void ast32(U32* p, U32 v) {
  __hip_atomic_store(p, v, __ATOMIC_RELAXED, __HIP_MEMORY_SCOPE_AGENT);
}
__device__ __forceinline__ void ast64(U64* p, U64 v) {
  __hip_atomic_store(p, v, __ATOMIC_RELAXED, __HIP_MEMORY_SCOPE_AGENT);
}
#define VM0 asm volatile("s_waitcnt vmcnt(0)" ::: "memory")

// ---------------------------------------------------------------------------
// One-time weight prep
// ---------------------------------------------------------------------------
__global__ __launch_bounds__(256) void pw_convert(
    const float* __restrict__ W, unsigned short* __restrict__ Wb) {
  size_t i = ((size_t)blockIdx.x * 256 + threadIdx.x) * 8;
  float4 a = *(const float4*)(W + i);
  float4 b = *(const float4*)(W + i + 4);
  short8 o;
  o[0] = (short)f2bf(a.x); o[1] = (short)f2bf(a.y);
  o[2] = (short)f2bf(a.z); o[3] = (short)f2bf(a.w);
  o[4] = (short)f2bf(b.x); o[5] = (short)f2bf(b.y);
  o[6] = (short)f2bf(b.z); o[7] = (short)f2bf(b.w);
  *(short8*)(Wb + i) = o;
}

// WcatT[k][j] bf16: k<384 -> W_ih[j][k], else W_hh[j][k-384].  [640][1024]
__global__ __launch_bounds__(256) void pw_catT(
    const float* __restrict__ W_ih, const float* __restrict__ W_hh,
    unsigned short* __restrict__ WcatT) {
  int gid = blockIdx.x * 256 + threadIdx.x;  // 655,360
  int k = gid >> 10, j = gid & 1023;
  float v = (k < CE + CH) ? W_ih[(size_t)j * (CE + CH) + k]
                          : W_hh[(size_t)j * CH + (k - (CE + CH))];
  WcatT[gid] = f2bf(v);
}

// 256x256 fp32 transpose: out[j][k] = in[k][j]
__global__ __launch_bounds__(256) void pw_t256(const float* __restrict__ in,
                                               float* __restrict__ out) {
  int j = blockIdx.x, k = threadIdx.x;
  out[j * CH + k] = in[k * CH + j];
}

// ---------------------------------------------------------------------------
// P0: Wh_h16 (bf16) = enc @ W_h^T (coalesced via W_hT); copy_idx.
// ---------------------------------------------------------------------------
__global__ __launch_bounds__(256) void p0_precompute(
    const float* __restrict__ enc, const float* __restrict__ W_hT,
    const int* __restrict__ src_ids, const int* __restrict__ src_oov,
    unsigned short* __restrict__ Wh_h16, int* __restrict__ copy_idx) {
  const int row0 = blockIdx.x * 8, tid = threadIdx.x;
  __shared__ float erT[CH * 8];
#pragma unroll
  for (int i = 0; i < 8; ++i) {
    int idx = tid + i * 256;
    int r = idx >> 8, j = idx & 255;
    erT[j * 8 + r] = enc[(size_t)row0 * CH + idx];
  }
  if (tid < 8) {
    int row = row0 + tid;
    int ov = src_oov[row];
    copy_idx[row] = (ov >= 0) ? (CV + ov) : src_ids[row];
  }
  __syncthreads();
  float acc[8] = {0, 0, 0, 0, 0, 0, 0, 0};
#pragma unroll 4
  for (int j = 0; j < CH; ++j) {
    float w = W_hT[j * CH + tid];
    float4 e0 = *(const float4*)&erT[j * 8];
    float4 e1 = *(const float4*)&erT[j * 8 + 4];
    acc[0] += e0.x * w; acc[1] += e0.y * w; acc[2] += e0.z * w; acc[3] += e0.w * w;
    acc[4] += e1.x * w; acc[5] += e1.y * w; acc[6] += e1.z * w; acc[7] += e1.w * w;
  }
#pragma unroll
  for (int r = 0; r < 8; ++r)
    Wh_h16[(size_t)(row0 + r) * CH + tid] = f2bf(acc[r]);
}

// ---------------------------------------------------------------------------
// Z: zero control words + rowsum partials (every call: replay-safe).
// ctrl: arrive[16 slots, stride 16] @0 ; release[64 replicas, stride 16] @256
// ---------------------------------------------------------------------------
__global__ __launch_bounds__(256) void z_init(U32* __restrict__ ctrl,
                                              float* __restrict__ part) {
  int tid = blockIdx.x * 256 + threadIdx.x;
  if (tid < 2048) ctrl[tid] = 0u;
  for (int i = tid; i < CTM1 * CB * 64; i += 256 * 64) part[i] = 0.f;
}

// ---------------------------------------------------------------------------
// MEGA: 16 independent state blocks + 1 aggregator + 767 vocab workers.
// Producers publish A-slab with UC stores; consumers read it CACHED
// (first-touch-per-replay ordering makes this safe; see round-9 theory).
// ---------------------------------------------------------------------------
__global__ __launch_bounds__(256, 4) void mega(
    const int* __restrict__ tgt, const float* __restrict__ hidden,
    const float* __restrict__ cell, const float* __restrict__ enc,
    const int* __restrict__ src_lens, const float* __restrict__ embedding,
    const float* __restrict__ w_c, const float* __restrict__ v_vec,
    const float* __restrict__ b_attn, const float* __restrict__ b_ih,
    const float* __restrict__ b_hh, const float* __restrict__ W_pg,
    const float* __restrict__ b_pg, const float* __restrict__ b_out,
    const unsigned short* __restrict__ Wh_h16, const float* __restrict__ W_sT,
    const unsigned short* __restrict__ WcatT,
    const unsigned short* __restrict__ Wb, U64* __restrict__ A64,
    unsigned short* __restrict__ attn16, float* __restrict__ p_gen_g,
    float* __restrict__ part, float* __restrict__ covloss_b,
    U32* __restrict__ ctrl, float* __restrict__ dout) {
  const int bid = blockIdx.x, tid = threadIdx.x;
  const int lane = tid & 63, wv = tid >> 6;
  U32* arrive = ctrl;          // 16 slots, stride 16
  U32* release = ctrl + 256;   // 64 replicas, stride 16

  __shared__ __align__(16) U64 sh_big[2080];  // vocab: A LDS [16][130]
  __shared__ float cov_s[CS];
  __shared__ float a_s[CS];
  __shared__ __align__(16) float h_cur[CH];
  __shared__ float hws_s[CH];
  __shared__ __align__(16) float ctx_s[CH];
  __shared__ float x_f[CX];
  __shared__ float g_sh[4 * CH];
  __shared__ float red[4];
  __shared__ float stat[4];
  __shared__ float prs[4][16];
  __shared__ float rsum_loc[16];

  if (bid < NST) {
    // ============== STATE LANE (batch b) — no cross-block waits ==========
    const int b = bid;
    const int len = src_lens[b];
    const float ba = b_attn[0];
    const int k4 = lane * 4;
    const float4 wc4 = *(const float4*)(w_c + k4);
    const float4 vv4 = *(const float4*)(v_vec + k4);
    float bias0 = b_ih[tid * 4] + b_hh[tid * 4];
    float bias1 = b_ih[tid * 4 + 1] + b_hh[tid * 4 + 1];
    float bias2 = b_ih[tid * 4 + 2] + b_hh[tid * 4 + 2];
    float bias3 = b_ih[tid * 4 + 3] + b_hh[tid * 4 + 3];
    float covl = 0.f;
    float c_reg = cell[b * CH + tid];

    for (int i = tid; i < CS; i += 256) cov_s[i] = 0.f;
    h_cur[tid] = hidden[b * CH + tid];
    __syncthreads();
    {
      float acc = 0.f;
#pragma unroll 8
      for (int j = 0; j < CH; ++j) acc += h_cur[j] * W_sT[j * CH + tid];
      hws_s[tid] = acc;
    }
    __syncthreads();

    for (int t = 0; t < CTM1; ++t) {
      // -- coverage update + covloss(t-1)
      if (t > 0) {
        for (int s = tid; s < CS; s += 256) {
          float a = a_s[s], cv = cov_s[s];
          covl += fminf(a, cv);
          cov_s[s] = cv + a;
        }
        __syncthreads();
      }
      // -- scores (no-max exp): wave per s, lanes over k (bf16 Wh_h)
      float ps = 0.f;
      for (int s = wv; s < CS; s += 4) {
        float cv = cov_s[s];
        U64 wq = *(const U64*)(Wh_h16 + ((size_t)(b * CS + s)) * CH + k4);
        float p =
            ftanh(bf2f((unsigned short)wq) + hws_s[k4] + cv * wc4.x + ba) *
                vv4.x +
            ftanh(bf2f((unsigned short)(wq >> 16)) + hws_s[k4 + 1] +
                  cv * wc4.y + ba) *
                vv4.y +
            ftanh(bf2f((unsigned short)(wq >> 32)) + hws_s[k4 + 2] +
                  cv * wc4.z + ba) *
                vv4.z +
            ftanh(bf2f((unsigned short)(wq >> 48)) + hws_s[k4 + 3] +
                  cv * wc4.w + ba) *
                vv4.w;
        p = wave_sum(p);
        if (lane == 0) {
          float e = (s < len) ? __expf(p) : 0.f;  // |score| <~ 10: safe
          a_s[s] = e;
          ps += e;
        }
      }
      if (lane == 0) red[wv] = ps;
      __syncthreads();
      if (tid == 0) stat[0] = 1.f / (red[0] + red[1] + red[2] + red[3]);
      __syncthreads();
      const float inv = stat[0];
      for (int s = tid; s < CS; s += 256) {
        float a = a_s[s] * inv;
        a_s[s] = a;
        attn16[((size_t)t * CB + b) * CS + s] = f2bf(a);
      }
      __syncthreads();
      // -- context (thread owns k=tid), x assembly
      {
        float pc = 0.f;
        const float* er = enc + ((size_t)b * CS) * CH + tid;
#pragma unroll 16
        for (int s = 0; s < CS; ++s) pc += a_s[s] * er[(size_t)s * CH];
        ctx_s[tid] = pc;
        x_f[CE + tid] = pc;
        x_f[CE + CH + tid] = h_cur[tid];
      }
      const int tok = tgt[b * CT + t];
      float emb_v = 0.f;
      if (tid < CE) {
        emb_v = embedding[(size_t)tok * CE + tid];
        x_f[tid] = emb_v;
      }
      __syncthreads();
      // -- gates (batch-local GEMV, bf16 WcatT stream): cols tid*4..+3
      {
        float a0 = 0.f, a1 = 0.f, a2 = 0.f, a3 = 0.f;
        const U64* wt = (const U64*)WcatT;
#pragma unroll 4
        for (int k = 0; k < CX; ++k) {
          U64 w = wt[(size_t)k * 256 + tid];
          float xk = x_f[k];
          a0 += xk * bf2f((unsigned short)w);
          a1 += xk * bf2f((unsigned short)(w >> 16));
          a2 += xk * bf2f((unsigned short)(w >> 32));
          a3 += xk * bf2f((unsigned short)(w >> 48));
        }
        g_sh[tid * 4] = a0 + bias0;
        g_sh[tid * 4 + 1] = a1 + bias1;
        g_sh[tid * 4 + 2] = a2 + bias2;
        g_sh[tid * 4 + 3] = a3 + bias3;
      }
      __syncthreads();
      // -- cell update (thread owns unit u=tid)
      float hn;
      {
        float gi = g_sh[tid], gf = g_sh[CH + tid];
        float gg2 = g_sh[2 * CH + tid], go = g_sh[3 * CH + tid];
        float cn = sigm(gf) * c_reg + sigm(gi) * ftanh(gg2);
        c_reg = cn;
        hn = sigm(go) * ftanh(cn);
        h_cur[tid] = hn;
      }
      __syncthreads();
      // -- publish A row b = [h|ctx] bf16, SINGLE copy, UC stores
      if (tid < 64) {
        ast64(&A64[(size_t)t * 2048 + b * 128 + tid],
              pack4(h_cur[4 * tid], h_cur[4 * tid + 1], h_cur[4 * tid + 2],
                    h_cur[4 * tid + 3]));
      } else if (tid < 128) {
        int i = tid - 64;
        ast64(&A64[(size_t)t * 2048 + b * 128 + 64 + i],
              pack4(ctx_s[4 * i], ctx_s[4 * i + 1], ctx_s[4 * i + 2],
                    ctx_s[4 * i + 3]));
      }
      VM0;
      if (tid == 0) ast32(&arrive[b * 16], (U32)(t + 1));
      // -- off-critical-path: hWs(next) + p_gen
      {
        float acc = 0.f;
#pragma unroll 8
        for (int j = 0; j < CH; ++j) acc += h_cur[j] * W_sT[j * CH + tid];
        hws_s[tid] = acc;
      }
      {
        float z = hn * W_pg[tid] + ctx_s[tid] * W_pg[CH + tid];
        if (tid < CE) z += emb_v * W_pg[2 * CH + tid];
        z = wave_sum(z);
        if (lane == 0) red[wv] = z;
        __syncthreads();
        if (tid == 0)
          p_gen_g[t * CB + b] =
              sigm(red[0] + red[1] + red[2] + red[3] + b_pg[0]);
      }
      __syncthreads();
    }
    // tail: covloss t=49 term, totals, hT/cT straight into dout
    for (int s = tid; s < CS; s += 256) covl += fminf(a_s[s], cov_s[s]);
    covl = wave_sum(covl);
    if (lane == 0) red[wv] = covl;
    __syncthreads();
    if (tid == 0) covloss_b[b] = red[0] + red[1] + red[2] + red[3];
    const size_t D0 = (size_t)CB * CTM1 * CEXT;
    dout[D0 + b * CH + tid] = h_cur[tid];
    dout[D0 + CB * CH + b * CH + tid] = c_reg;
  } else if (bid == NST) {
    // ===================== AGGREGATOR (1 block) ==========================
    for (int t = 0; t < CTM1; ++t) {
      if (wv == 0) {
        int gg = 0;
        while (gg < (1 << 20)) {
          U32 v = (lane < NST) ? ald32(&arrive[lane * 16]) : (U32)(t + 1);
          if (__all(v >= (U32)(t + 1))) break;
          __builtin_amdgcn_s_sleep(8);
          ++gg;
        }
      }
      __syncthreads();
      if (tid < 64) ast32(&release[tid * 16], (U32)(t + 1));
      __syncthreads();
    }
  } else {
    // ===================== VOCAB WORKERS (767 blocks) ====================
    const int vb = bid - NST - 1;
    const int rep = vb & 63;
    const int nn = lane & 15, g = lane >> 4;
    U64* a64l = sh_big;  // [16][130] u64 (65-short8 row stride)
    const short8* lds8 = (const short8*)sh_big;
    for (int t = 0; t < CTM1; ++t) {
      if (tid == 0) {  // poll own replica line (UC — must see fresh)
        int gg = 0;
        while (ald32(&release[rep * 16]) < (U32)(t + 1) && ++gg < (1 << 18))
          __builtin_amdgcn_s_sleep(32);
      }
      __syncthreads();
      {  // stage A slab via CACHED loads (first touch this replay -> fresh)
        const U64* src = A64 + (size_t)t * 2048;
#pragma unroll
        for (int i = 0; i < 8; ++i) {
          int idx = tid + i * 256;
          int row = idx >> 7, col = idx & 127;
          a64l[row * 130 + col] = src[idx];
        }
      }
      if (tid < 16) rsum_loc[tid] = 0.f;
      __syncthreads();
      short8 af[16];
#pragma unroll
      for (int kt = 0; kt < 16; ++kt) af[kt] = lds8[nn * 65 + kt * 4 + g];
      for (int tile = vb; tile < NTILE; tile += NWK) {
        int v = tile * 64 + wv * 16 + nn;
        bool ok = v < CV;
        int vc = ok ? v : CV - 1;
        const short8* bp = (const short8*)Wb + (size_t)vc * 64;  // cached
        f32x4 acc = {0.f, 0.f, 0.f, 0.f};
#pragma unroll
        for (int kt = 0; kt < 16; ++kt)
          acc = __builtin_amdgcn_mfma_f32_16x16x32_bf16(af[kt], bp[kt * 4 + g],
                                                        acc, 0, 0, 0);
        float bo = ok ? b_out[v] : 0.f;
        float ev[4];
#pragma unroll
        for (int r = 0; r < 4; ++r) {
          float e = ok ? __expf(acc[r] + bo) : 0.f;
          if (ok) dout[((size_t)((g * 4 + r) * CTM1 + t)) * CEXT + v] = e;
#pragma unroll
          for (int o = 1; o < 16; o <<= 1) e += __shfl_xor(e, o);
          ev[r] = e;
        }
        if (nn == 0) {
#pragma unroll
          for (int r = 0; r < 4; ++r) prs[wv][g * 4 + r] = ev[r];
        }
        __syncthreads();
        if (tid < 16)
          rsum_loc[tid] +=
              prs[0][tid] + prs[1][tid] + prs[2][tid] + prs[3][tid];
        __syncthreads();
      }
      if (tid < 16)
        atomicAdd(&part[((size_t)t * CB + tid) * 64 + rep], rsum_loc[tid]);
    }
  }
}

// ---------------------------------------------------------------------------
// POST 1: per (b,t) row: reduce 64 rowsum partials, normalize + zero pads.
// ---------------------------------------------------------------------------
__global__ __launch_bounds__(256) void post_norm(
    const float* __restrict__ part, const float* __restrict__ p_gen_g,
    float* __restrict__ dout) {
  const int R = blockIdx.x;
  const int b = R / CTM1, t = R % CTM1;
  const int tid = threadIdx.x;
  __shared__ float stat;
  float s = (tid < 64) ? part[((size_t)t * CB + b) * 64 + tid] : 0.f;
  s = wave_sum(s);
  if (tid == 0) stat = p_gen_g[t * CB + b] / s;
  __syncthreads();
  float inv = stat;
  float* drow = dout + (size_t)R * CEXT;
  for (int v = tid; v < CEXT; v += 256)
    drow[v] = (v < CV) ? drow[v] * inv : 0.f;
}

// ---------------------------------------------------------------------------
// POST 2: copy-dist scatter for all t + coverage_loss. grid = 16.
// ---------------------------------------------------------------------------
__global__ __launch_bounds__(256) void post_tail(
    const unsigned short* __restrict__ attn16,
    const float* __restrict__ p_gen_g, const int* __restrict__ copy_idx,
    const float* __restrict__ covloss_b, float* __restrict__ dout) {
  const int b = blockIdx.x, tid = threadIdx.x;
  for (int t = 0; t < CTM1; ++t) {
    float pg1 = 1.f - p_gen_g[t * CB + b];
    const unsigned short* ar = attn16 + ((size_t)t * CB + b) * CS;
    float* drow = dout + ((size_t)(b * CTM1 + t)) * CEXT;
    for (int s = tid; s < CS; s += 256)
      atomicAdd(drow + copy_idx[b * CS + s], pg1 * bf2f(ar[s]));
  }
  if (b == 0 && tid == 0) {
    const size_t D0 = (size_t)CB * CTM1 * CEXT;
    float s = 0.f;
    for (int i = 0; i < CB; ++i) s += covloss_b[i];
    dout[D0 + 2 * CB * CH] = s / (float)(CTM1 * CB);
  }
}

// ---------------------------------------------------------------------------
extern "C" void kernel_launch(void* const* d_in, const int* in_sizes, int n_in,
                              void* d_out, int out_size, void* d_ws,
                              size_t ws_size, hipStream_t stream) {
  const int* tgt = (const int*)d_in[0];
  const float* hidden = (const float*)d_in[1];
  const float* cell = (const float*)d_in[2];
  const float* enc = (const float*)d_in[3];
  const int* src_lens = (const int*)d_in[4];
  const int* src_ids = (const int*)d_in[5];
  const int* src_oov = (const int*)d_in[6];
  const float* embedding = (const float*)d_in[7];
  const float* W_h = (const float*)d_in[8];
  const float* W_s = (const float*)d_in[9];
  const float* w_c = (const float*)d_in[10];
  const float* v_vec = (const float*)d_in[11];
  const float* b_attn = (const float*)d_in[12];
  const float* W_ih = (const float*)d_in[13];
  const float* W_hh = (const float*)d_in[14];
  const float* b_ih = (const float*)d_in[15];
  const float* b_hh = (const float*)d_in[16];
  const float* W_pg = (const float*)d_in[17];
  const float* b_pg = (const float*)d_in[18];
  const float* W_out = (const float*)d_in[19];
  const float* b_out = (const float*)d_in[20];
  float* dout = (float*)d_out;

  // workspace layout (A64 8B-aligned: word count before it is even)
  float* ws = (float*)d_ws;
  float* W_sT = ws;                                  // 65,536 f
  float* W_hT = W_sT + CH * CH;                      // 65,536 f
  float* p_gen_g = W_hT + CH * CH;                   // 800 f
  float* part = p_gen_g + CTM1 * CB;                 // 51,200 f
  float* covloss_b = part + CTM1 * CB * 64;          // 16 f
  int* copy_idx = (int*)(covloss_b + 16);            // 6,400 i
  U32* ctrl = (U32*)(copy_idx + CB * CS);            // 2,048 u32
  U64* A64 = (U64*)(ctrl + 2048);                    // 102,400 u64
  unsigned short* attn16 =
      (unsigned short*)(A64 + (size_t)CTM1 * 2048);  // 320,000 sh
  unsigned short* Wh_h16 = attn16 + (size_t)CTM1 * CB * CS;     // 1,638,400 sh
  unsigned short* WcatT = Wh_h16 + (size_t)CB * CS * CH;        // 655,360 sh
  unsigned short* Wb = WcatT + (size_t)CX * 1024;    // 25,600,000 sh

  z_init<<<64, 256, 0, stream>>>(ctrl, part);
  pw_convert<<<(CV * 2 * CH) / (256 * 8), 256, 0, stream>>>(W_out, Wb);
  pw_catT<<<(CX * 1024) / 256, 256, 0, stream>>>(W_ih, W_hh, WcatT);
  pw_t256<<<CH, CH, 0, stream>>>(W_s, W_sT);
  pw_t256<<<CH, CH, 0, stream>>>(W_h, W_hT);
  p0_precompute<<<CB * CS / 8, 256, 0, stream>>>(enc, W_hT, src_ids, src_oov,
                                                 Wh_h16, copy_idx);

  void* kargs[] = {
      (void*)&tgt,      (void*)&hidden,    (void*)&cell,     (void*)&enc,
      (void*)&src_lens, (void*)&embedding, (void*)&w_c,      (void*)&v_vec,
      (void*)&b_attn,   (void*)&b_ih,      (void*)&b_hh,     (void*)&W_pg,
      (void*)&b_pg,     (void*)&b_out,     (void*)&Wh_h16,   (void*)&W_sT,
      (void*)&WcatT,    (void*)&Wb,        (void*)&A64,      (void*)&attn16,
      (void*)&p_gen_g,  (void*)&part,      (void*)&covloss_b,(void*)&ctrl,
      (void*)&dout};
  hipError_t e = hipLaunchCooperativeKernel((const void*)mega, dim3(NBLK),
                                            dim3(256), kargs, 0, stream);
  if (e != hipSuccess) {
    hipLaunchKernelGGL(mega, dim3(NBLK), dim3(256), 0, stream, tgt, hidden,
                       cell, enc, src_lens, embedding, w_c, v_vec, b_attn,
                       b_ih, b_hh, W_pg, b_pg, b_out, Wh_h16, W_sT, WcatT, Wb,
                       A64, attn16, p_gen_g, part, covloss_b, ctrl, dout);
  }
  post_norm<<<CB * CTM1, 256, 0, stream>>>(part, p_gen_g, dout);
  post_tail<<<CB, 256, 0, stream>>>(attn16, p_gen_g, copy_idx, covloss_b,
                                    dout);
}

// Round 10
// 2673.587 us; speedup vs baseline: 2.9018x; 2.8862x over previous
//
#include <hip/hip_runtime.h>
#include <math.h>

// Problem constants
#define CB 16
#define CS 400
#define CT 51
#define CTM1 50
#define CV 50000
#define CE 128
#define CH 256
#define CMAXOOV 50
#define CEXT (CV + CMAXOOV)
#define CX 640             // E + H + H  (x = [emb|ctx|h])
#define NST 16             // state blocks
#define NWK 239            // vocab worker blocks (1024 thr, 4 tiles each)
#define NBLK 256           // 16 state + 1 aggregator + 239 workers
#define NTILE 782          // ceil(V/64)

typedef __attribute__((ext_vector_type(4))) float f32x4;
typedef __attribute__((ext_vector_type(8))) short short8;
typedef unsigned int U32;
typedef unsigned long long U64;

__device__ __forceinline__ float wave_sum(float x) {
#pragma unroll
  for (int o = 32; o > 0; o >>= 1) x += __shfl_xor(x, o);
  return x;
}
__device__ __forceinline__ float sigm(float x) {
  return 1.f / (1.f + __expf(-x));
}
__device__ __forceinline__ float ftanh(float x) {
  x = fminf(fmaxf(x, -15.f), 15.f);
  float e = __expf(2.f * x);
  return (e - 1.f) / (e + 1.f);
}
__device__ __forceinline__ unsigned short f2bf(float f) {
  union { float f; U32 u; } x;
  x.f = f;
  U32 r = x.u + 0x7FFFu + ((x.u >> 16) & 1u);  // RNE
  return (unsigned short)(r >> 16);
}
__device__ __forceinline__ float bf2f(unsigned short u) {
  return __uint_as_float(((U32)u) << 16);
}
__device__ __forceinline__ U64 pack4(float a, float b, float c, float d) {
  return (U64)f2bf(a) | ((U64)f2bf(b) << 16) | ((U64)f2bf(c) << 32) |
         ((U64)f2bf(d) << 48);
}
// uncached (device-coherent) ops — flags + producer-side publishes ONLY
__device__ __forceinline__ U32 ald32(const U32* p) {
  return __hip_atomic_load(p, __ATOMIC_RELAXED, __HIP_MEMORY_SCOPE_AGENT);
}
__device__ __forceinline__ void ast32(U32* p, U32 v) {
  __hip_atomic_store(p, v, __ATOMIC_RELAXED, __HIP_MEMORY_SCOPE_AGENT);
}
__device__ __forceinline__ void ast64(U64* p, U64 v) {
  __hip_atomic_store(p, v, __ATOMIC_RELAXED, __HIP_MEMORY_SCOPE_AGENT);
}
#define VM0 asm volatile("s_waitcnt vmcnt(0)" ::: "memory")

// ---------------------------------------------------------------------------
// One-time weight prep
// ---------------------------------------------------------------------------
__global__ __launch_bounds__(256) void pw_convert(
    const float* __restrict__ W, unsigned short* __restrict__ Wb) {
  size_t i = ((size_t)blockIdx.x * 256 + threadIdx.x) * 8;
  float4 a = *(const float4*)(W + i);
  float4 b = *(const float4*)(W + i + 4);
  short8 o;
  o[0] = (short)f2bf(a.x); o[1] = (short)f2bf(a.y);
  o[2] = (short)f2bf(a.z); o[3] = (short)f2bf(a.w);
  o[4] = (short)f2bf(b.x); o[5] = (short)f2bf(b.y);
  o[6] = (short)f2bf(b.z); o[7] = (short)f2bf(b.w);
  *(short8*)(Wb + i) = o;
}

// WcatT[k][j] bf16: k<384 -> W_ih[j][k], else W_hh[j][k-384].  [640][1024]
__global__ __launch_bounds__(256) void pw_catT(
    const float* __restrict__ W_ih, const float* __restrict__ W_hh,
    unsigned short* __restrict__ WcatT) {
  int gid = blockIdx.x * 256 + threadIdx.x;  // 655,360
  int k = gid >> 10, j = gid & 1023;
  float v = (k < CE + CH) ? W_ih[(size_t)j * (CE + CH) + k]
                          : W_hh[(size_t)j * CH + (k - (CE + CH))];
  WcatT[gid] = f2bf(v);
}

// 256x256 fp32 transpose: out[j][k] = in[k][j]
__global__ __launch_bounds__(256) void pw_t256(const float* __restrict__ in,
                                               float* __restrict__ out) {
  int j = blockIdx.x, k = threadIdx.x;
  out[j * CH + k] = in[k * CH + j];
}

// ---------------------------------------------------------------------------
// P0: Wh_h16 (bf16) = enc @ W_h^T (coalesced via W_hT); copy_idx.
// ---------------------------------------------------------------------------
__global__ __launch_bounds__(256) void p0_precompute(
    const float* __restrict__ enc, const float* __restrict__ W_hT,
    const int* __restrict__ src_ids, const int* __restrict__ src_oov,
    unsigned short* __restrict__ Wh_h16, int* __restrict__ copy_idx) {
  const int row0 = blockIdx.x * 8, tid = threadIdx.x;
  __shared__ float erT[CH * 8];
#pragma unroll
  for (int i = 0; i < 8; ++i) {
    int idx = tid + i * 256;
    int r = idx >> 8, j = idx & 255;
    erT[j * 8 + r] = enc[(size_t)row0 * CH + idx];
  }
  if (tid < 8) {
    int row = row0 + tid;
    int ov = src_oov[row];
    copy_idx[row] = (ov >= 0) ? (CV + ov) : src_ids[row];
  }
  __syncthreads();
  float acc[8] = {0, 0, 0, 0, 0, 0, 0, 0};
#pragma unroll 4
  for (int j = 0; j < CH; ++j) {
    float w = W_hT[j * CH + tid];
    float4 e0 = *(const float4*)&erT[j * 8];
    float4 e1 = *(const float4*)&erT[j * 8 + 4];
    acc[0] += e0.x * w; acc[1] += e0.y * w; acc[2] += e0.z * w; acc[3] += e0.w * w;
    acc[4] += e1.x * w; acc[5] += e1.y * w; acc[6] += e1.z * w; acc[7] += e1.w * w;
  }
#pragma unroll
  for (int r = 0; r < 8; ++r)
    Wh_h16[(size_t)(row0 + r) * CH + tid] = f2bf(acc[r]);
}

// ---------------------------------------------------------------------------
// Z: zero control words + rowsum partials (every call: replay-safe).
// ctrl: arrive[16 slots, stride 16] @0 ; release[64 replicas, stride 16] @256
// ---------------------------------------------------------------------------
__global__ __launch_bounds__(256) void z_init(U32* __restrict__ ctrl,
                                              float* __restrict__ part) {
  int tid = blockIdx.x * 256 + threadIdx.x;
  if (tid < 2048) ctrl[tid] = 0u;
  for (int i = tid; i < CTM1 * CB * 64; i += 256 * 64) part[i] = 0.f;
}

// ---------------------------------------------------------------------------
// MEGA: 16 state blocks (1024 thr, 16 waves — latency hiding) + 1 aggregator
// + 239 vocab workers (1024 thr, 4 tiles each, single pass).
// ---------------------------------------------------------------------------
__global__ __launch_bounds__(1024, 4) void mega(
    const int* __restrict__ tgt, const float* __restrict__ hidden,
    const float* __restrict__ cell, const float* __restrict__ enc,
    const int* __restrict__ src_lens, const float* __restrict__ embedding,
    const float* __restrict__ w_c, const float* __restrict__ v_vec,
    const float* __restrict__ b_attn, const float* __restrict__ b_ih,
    const float* __restrict__ b_hh, const float* __restrict__ W_pg,
    const float* __restrict__ b_pg, const float* __restrict__ b_out,
    const unsigned short* __restrict__ Wh_h16, const float* __restrict__ W_sT,
    const unsigned short* __restrict__ WcatT,
    const unsigned short* __restrict__ Wb, U64* __restrict__ A64,
    unsigned short* __restrict__ attn16, float* __restrict__ p_gen_g,
    float* __restrict__ part, float* __restrict__ covloss_b,
    U32* __restrict__ ctrl, float* __restrict__ dout) {
  const int bid = blockIdx.x, tid = threadIdx.x;
  const int lane = tid & 63, wv = tid >> 6;  // 16 waves
  U32* arrive = ctrl;          // 16 slots, stride 16
  U32* release = ctrl + 256;   // 64 replicas, stride 16

  __shared__ __align__(16) U64 sh_big[2080];  // worker: A LDS / state: gp
  __shared__ float cov_s[CS];
  __shared__ float a_s[CS];
  __shared__ __align__(16) float h_cur[CH];
  __shared__ float hws_s[CH];
  __shared__ __align__(16) float ctx_s[CH];
  __shared__ float x_f[CX];
  __shared__ float g_sh[4 * CH];
  __shared__ float pctx[4 * CH];   // 4-group partials (ctx / hWs)
  __shared__ float red[16];
  __shared__ float stat[4];
  __shared__ float prs[16][16];
  __shared__ float rsum_loc[16];

  if (bid < NST) {
    // ============== STATE LANE (batch b), 16 waves ==============
    const int b = bid;
    const int len = src_lens[b];
    const float ba = b_attn[0];
    const int k4 = lane * 4;
    const float4 wc4 = *(const float4*)(w_c + k4);
    const float4 vv4 = *(const float4*)(v_vec + k4);
    const float bias_reg = b_ih[tid] + b_hh[tid];  // col tid of 4H=1024
    const int kg = tid & 255, grp = tid >> 8;      // 4 groups of 256
    float covl = 0.f;
    float c_reg = (tid < CH) ? cell[b * CH + tid] : 0.f;
    float* gp = (float*)sh_big;  // [4][1024] gates partials (16 KB)

    if (tid < CS) cov_s[tid] = 0.f;
    if (tid < CH) h_cur[tid] = hidden[b * CH + tid];
    __syncthreads();
    {  // hWs init: group grp handles j in [grp*64, grp*64+64)
      float acc = 0.f;
#pragma unroll 8
      for (int j = grp * 64; j < grp * 64 + 64; ++j)
        acc += h_cur[j] * W_sT[j * CH + kg];
      pctx[grp * CH + kg] = acc;
    }
    __syncthreads();
    if (tid < CH)
      hws_s[tid] = pctx[tid] + pctx[CH + tid] + pctx[2 * CH + tid] +
                   pctx[3 * CH + tid];
    __syncthreads();

    for (int t = 0; t < CTM1; ++t) {
      // -- coverage update + covloss(t-1)  (single shot, tid<CS)
      if (t > 0) {
        if (tid < CS) {
          float a = a_s[tid], cv = cov_s[tid];
          covl += fminf(a, cv);
          cov_s[tid] = cv + a;
        }
        __syncthreads();
      }
      // -- scores (no-max exp): wave per s (25 iters/wave)
      float ps = 0.f;
      for (int s = wv; s < CS; s += 16) {
        float cv = cov_s[s];
        U64 wq = *(const U64*)(Wh_h16 + ((size_t)(b * CS + s)) * CH + k4);
        float p =
            ftanh(bf2f((unsigned short)wq) + hws_s[k4] + cv * wc4.x + ba) *
                vv4.x +
            ftanh(bf2f((unsigned short)(wq >> 16)) + hws_s[k4 + 1] +
                  cv * wc4.y + ba) *
                vv4.y +
            ftanh(bf2f((unsigned short)(wq >> 32)) + hws_s[k4 + 2] +
                  cv * wc4.z + ba) *
                vv4.z +
            ftanh(bf2f((unsigned short)(wq >> 48)) + hws_s[k4 + 3] +
                  cv * wc4.w + ba) *
                vv4.w;
        p = wave_sum(p);
        if (lane == 0) {
          float e = (s < len) ? __expf(p) : 0.f;  // |score| <~ 10: safe
          a_s[s] = e;
          ps += e;
        }
      }
      if (lane == 0) red[wv] = ps;
      __syncthreads();
      if (tid == 0) {
        float s2 = 0.f;
#pragma unroll
        for (int i = 0; i < 16; ++i) s2 += red[i];
        stat[0] = 1.f / s2;
      }
      __syncthreads();
      const float inv = stat[0];
      if (tid < CS) {
        float a = a_s[tid] * inv;
        a_s[tid] = a;
        attn16[((size_t)t * CB + b) * CS + tid] = f2bf(a);
      }
      __syncthreads();
      // -- context: group grp handles s in [grp*100, grp*100+100)
      {
        float pc = 0.f;
        const float* er = enc + ((size_t)(b * CS + grp * 100)) * CH + kg;
#pragma unroll 10
        for (int i = 0; i < 100; ++i)
          pc += a_s[grp * 100 + i] * er[(size_t)i * CH];
        pctx[grp * CH + kg] = pc;
      }
      __syncthreads();
      const int tok = tgt[b * CT + t];
      float emb_v = 0.f;
      if (tid < CH) {
        float cx = pctx[tid] + pctx[CH + tid] + pctx[2 * CH + tid] +
                   pctx[3 * CH + tid];
        ctx_s[tid] = cx;
        x_f[CE + tid] = cx;
        x_f[CE + CH + tid] = h_cur[tid];
      }
      if (tid < CE) {
        emb_v = embedding[(size_t)tok * CE + tid];
        x_f[tid] = emb_v;
      }
      __syncthreads();
      // -- gates: group grp handles k in [grp*160, grp*160+160); 4 cols/thread
      {
        float a0 = 0.f, a1 = 0.f, a2 = 0.f, a3 = 0.f;
        const U64* wt = (const U64*)WcatT;
#pragma unroll 4
        for (int k = grp * 160; k < grp * 160 + 160; ++k) {
          U64 w = wt[(size_t)k * 256 + kg];
          float xk = x_f[k];
          a0 += xk * bf2f((unsigned short)w);
          a1 += xk * bf2f((unsigned short)(w >> 16));
          a2 += xk * bf2f((unsigned short)(w >> 32));
          a3 += xk * bf2f((unsigned short)(w >> 48));
        }
        gp[grp * 1024 + kg * 4] = a0;
        gp[grp * 1024 + kg * 4 + 1] = a1;
        gp[grp * 1024 + kg * 4 + 2] = a2;
        gp[grp * 1024 + kg * 4 + 3] = a3;
      }
      __syncthreads();
      g_sh[tid] = gp[tid] + gp[1024 + tid] + gp[2048 + tid] + gp[3072 + tid] +
                  bias_reg;
      __syncthreads();
      // -- cell update (tid<256 owns unit tid)
      if (tid < CH) {
        float gi = g_sh[tid], gf = g_sh[CH + tid];
        float gg2 = g_sh[2 * CH + tid], go = g_sh[3 * CH + tid];
        float cn = sigm(gf) * c_reg + sigm(gi) * ftanh(gg2);
        c_reg = cn;
        h_cur[tid] = sigm(go) * ftanh(cn);
      }
      __syncthreads();
      // -- publish A row b = [h|ctx] bf16 (UC stores), then arrive
      if (tid < 64) {
        ast64(&A64[(size_t)t * 2048 + b * 128 + tid],
              pack4(h_cur[4 * tid], h_cur[4 * tid + 1], h_cur[4 * tid + 2],
                    h_cur[4 * tid + 3]));
      } else if (tid < 128) {
        int i = tid - 64;
        ast64(&A64[(size_t)t * 2048 + b * 128 + 64 + i],
              pack4(ctx_s[4 * i], ctx_s[4 * i + 1], ctx_s[4 * i + 2],
                    ctx_s[4 * i + 3]));
      }
      VM0;
      __syncthreads();  // all waves' stores drained before flag
      if (tid == 0) ast32(&arrive[b * 16], (U32)(t + 1));
      // -- off-critical-path: hWs(next) + p_gen
      {
        float acc = 0.f;
#pragma unroll 8
        for (int j = grp * 64; j < grp * 64 + 64; ++j)
          acc += h_cur[j] * W_sT[j * CH + kg];
        pctx[grp * CH + kg] = acc;
      }
      __syncthreads();
      if (tid < CH)
        hws_s[tid] = pctx[tid] + pctx[CH + tid] + pctx[2 * CH + tid] +
                     pctx[3 * CH + tid];
      {
        float z = 0.f;
        if (tid < CH)
          z = h_cur[tid] * W_pg[tid] + ctx_s[tid] * W_pg[CH + tid];
        if (tid < CE) z += emb_v * W_pg[2 * CH + tid];
        z = wave_sum(z);
        if (lane == 0) red[wv] = z;
        __syncthreads();
        if (tid == 0) {
          float s2 = 0.f;
#pragma unroll
          for (int i = 0; i < 16; ++i) s2 += red[i];
          p_gen_g[t * CB + b] = sigm(s2 + b_pg[0]);
        }
      }
      __syncthreads();
    }
    // tail: covloss t=49 term, totals, hT/cT
    if (tid < CS) covl += fminf(a_s[tid], cov_s[tid]);
    covl = wave_sum(covl);
    if (lane == 0) red[wv] = covl;
    __syncthreads();
    if (tid == 0) {
      float s2 = 0.f;
#pragma unroll
      for (int i = 0; i < 16; ++i) s2 += red[i];
      covloss_b[b] = s2;
    }
    if (tid < CH) {
      const size_t D0 = (size_t)CB * CTM1 * CEXT;
      dout[D0 + b * CH + tid] = h_cur[tid];
      dout[D0 + CB * CH + b * CH + tid] = c_reg;
    }
  } else if (bid == NST) {
    // ===================== AGGREGATOR (1 block) ==========================
    for (int t = 0; t < CTM1; ++t) {
      if (wv == 0) {
        int gg = 0;
        while (gg < (1 << 20)) {
          U32 v = (lane < NST) ? ald32(&arrive[lane * 16]) : (U32)(t + 1);
          if (__all(v >= (U32)(t + 1))) break;
          __builtin_amdgcn_s_sleep(8);
          ++gg;
        }
      }
      __syncthreads();
      if (tid < 64) ast32(&release[tid * 16], (U32)(t + 1));
      __syncthreads();
    }
  } else {
    // ============ VOCAB WORKERS (239 blocks, 16 waves, 4 tiles) ==========
    const int vb = bid - NST - 1;
    const int rep = vb & 63;
    const int nn = lane & 15, g = lane >> 4;
    const int t4 = (wv >> 2) * NWK + vb;     // this wave's tile
    const int v = t4 * 64 + (wv & 3) * 16 + nn;
    const bool live = (t4 < NTILE) && (v < CV);
    const int vc = live ? v : CV - 1;
    U64* a64l = sh_big;  // [16][130] u64 (65-short8 row stride)
    const short8* lds8 = (const short8*)sh_big;
    const short8* bp = (const short8*)Wb + (size_t)vc * 64;  // cached
    const float bo = live ? b_out[v] : 0.f;
    for (int t = 0; t < CTM1; ++t) {
      if (tid == 0) {  // poll own replica line (UC)
        int gg = 0;
        while (ald32(&release[rep * 16]) < (U32)(t + 1) && ++gg < (1 << 18))
          __builtin_amdgcn_s_sleep(32);
      }
      __syncthreads();
      {  // stage A slab via CACHED loads (2 u64 per thread)
        const U64* src = A64 + (size_t)t * 2048;
#pragma unroll
        for (int i = 0; i < 2; ++i) {
          int idx = tid + i * 1024;
          int row = idx >> 7, col = idx & 127;
          a64l[row * 130 + col] = src[idx];
        }
      }
      __syncthreads();
      short8 af[16];
#pragma unroll
      for (int kt = 0; kt < 16; ++kt) af[kt] = lds8[nn * 65 + kt * 4 + g];
      f32x4 acc = {0.f, 0.f, 0.f, 0.f};
#pragma unroll
      for (int kt = 0; kt < 16; ++kt)
        acc = __builtin_amdgcn_mfma_f32_16x16x32_bf16(af[kt], bp[kt * 4 + g],
                                                      acc, 0, 0, 0);
      float ev[4];
#pragma unroll
      for (int r = 0; r < 4; ++r) {
        float e = live ? __expf(acc[r] + bo) : 0.f;
        if (live) dout[((size_t)((g * 4 + r) * CTM1 + t)) * CEXT + v] = e;
#pragma unroll
        for (int o = 1; o < 16; o <<= 1) e += __shfl_xor(e, o);
        ev[r] = e;
      }
      if (nn == 0) {
#pragma unroll
        for (int r = 0; r < 4; ++r) prs[wv][g * 4 + r] = ev[r];
      }
      __syncthreads();
      if (tid < 16) {
        float s = 0.f;
#pragma unroll
        for (int w = 0; w < 16; ++w) s += prs[w][tid];
        atomicAdd(&part[((size_t)t * CB + tid) * 64 + rep], s);
      }
      __syncthreads();
    }
  }
}

// ---------------------------------------------------------------------------
// POST 1: per (b,t) row: reduce 64 rowsum partials, normalize + zero pads.
// ---------------------------------------------------------------------------
__global__ __launch_bounds__(256) void post_norm(
    const float* __restrict__ part, const float* __restrict__ p_gen_g,
    float* __restrict__ dout) {
  const int R = blockIdx.x;
  const int b = R / CTM1, t = R % CTM1;
  const int tid = threadIdx.x;
  __shared__ float stat;
  float s = (tid < 64) ? part[((size_t)t * CB + b) * 64 + tid] : 0.f;
  s = wave_sum(s);
  if (tid == 0) stat = p_gen_g[t * CB + b] / s;
  __syncthreads();
  float inv = stat;
  float* drow = dout + (size_t)R * CEXT;
  for (int v = tid; v < CEXT; v += 256)
    drow[v] = (v < CV) ? drow[v] * inv : 0.f;
}

// ---------------------------------------------------------------------------
// POST 2: copy-dist scatter for all t + coverage_loss. grid = 16.
// ---------------------------------------------------------------------------
__global__ __launch_bounds__(256) void post_tail(
    const unsigned short* __restrict__ attn16,
    const float* __restrict__ p_gen_g, const int* __restrict__ copy_idx,
    const float* __restrict__ covloss_b, float* __restrict__ dout) {
  const int b = blockIdx.x, tid = threadIdx.x;
  for (int t = 0; t < CTM1; ++t) {
    float pg1 = 1.f - p_gen_g[t * CB + b];
    const unsigned short* ar = attn16 + ((size_t)t * CB + b) * CS;
    float* drow = dout + ((size_t)(b * CTM1 + t)) * CEXT;
    for (int s = tid; s < CS; s += 256)
      atomicAdd(drow + copy_idx[b * CS + s], pg1 * bf2f(ar[s]));
  }
  if (b == 0 && tid == 0) {
    const size_t D0 = (size_t)CB * CTM1 * CEXT;
    float s = 0.f;
    for (int i = 0; i < CB; ++i) s += covloss_b[i];
    dout[D0 + 2 * CB * CH] = s / (float)(CTM1 * CB);
  }
}

// ---------------------------------------------------------------------------
extern "C" void kernel_launch(void* const* d_in, const int* in_sizes, int n_in,
                              void* d_out, int out_size, void* d_ws,
                              size_t ws_size, hipStream_t stream) {
  const int* tgt = (const int*)d_in[0];
  const float* hidden = (const float*)d_in[1];
  const float* cell = (const float*)d_in[2];
  const float* enc = (const float*)d_in[3];
  const int* src_lens = (const int*)d_in[4];
  const int* src_ids = (const int*)d_in[5];
  const int* src_oov = (const int*)d_in[6];
  const float* embedding = (const float*)d_in[7];
  const float* W_h = (const float*)d_in[8];
  const float* W_s = (const float*)d_in[9];
  const float* w_c = (const float*)d_in[10];
  const float* v_vec = (const float*)d_in[11];
  const float* b_attn = (const float*)d_in[12];
  const float* W_ih = (const float*)d_in[13];
  const float* W_hh = (const float*)d_in[14];
  const float* b_ih = (const float*)d_in[15];
  const float* b_hh = (const float*)d_in[16];
  const float* W_pg = (const float*)d_in[17];
  const float* b_pg = (const float*)d_in[18];
  const float* W_out = (const float*)d_in[19];
  const float* b_out = (const float*)d_in[20];
  float* dout = (float*)d_out;

  // workspace layout
  float* ws = (float*)d_ws;
  float* W_sT = ws;                                  // 65,536 f
  float* W_hT = W_sT + CH * CH;                      // 65,536 f
  float* p_gen_g = W_hT + CH * CH;                   // 800 f
  float* part = p_gen_g + CTM1 * CB;                 // 51,200 f
  float* covloss_b = part + CTM1 * CB * 64;          // 16 f
  int* copy_idx = (int*)(covloss_b + 16);            // 6,400 i
  U32* ctrl = (U32*)(copy_idx + CB * CS);            // 2,048 u32
  U64* A64 = (U64*)(ctrl + 2048);                    // 102,400 u64
  unsigned short* attn16 =
      (unsigned short*)(A64 + (size_t)CTM1 * 2048);  // 320,000 sh
  unsigned short* Wh_h16 = attn16 + (size_t)CTM1 * CB * CS;     // 1,638,400 sh
  unsigned short* WcatT = Wh_h16 + (size_t)CB * CS * CH;        // 655,360 sh
  unsigned short* Wb = WcatT + (size_t)CX * 1024;    // 25,600,000 sh

  z_init<<<64, 256, 0, stream>>>(ctrl, part);
  pw_convert<<<(CV * 2 * CH) / (256 * 8), 256, 0, stream>>>(W_out, Wb);
  pw_catT<<<(CX * 1024) / 256, 256, 0, stream>>>(W_ih, W_hh, WcatT);
  pw_t256<<<CH, CH, 0, stream>>>(W_s, W_sT);
  pw_t256<<<CH, CH, 0, stream>>>(W_h, W_hT);
  p0_precompute<<<CB * CS / 8, 256, 0, stream>>>(enc, W_hT, src_ids, src_oov,
                                                 Wh_h16, copy_idx);

  void* kargs[] = {
      (void*)&tgt,      (void*)&hidden,    (void*)&cell,     (void*)&enc,
      (void*)&src_lens, (void*)&embedding, (void*)&w_c,      (void*)&v_vec,
      (void*)&b_attn,   (void*)&b_ih,      (void*)&b_hh,     (void*)&W_pg,
      (void*)&b_pg,     (void*)&b_out,     (void*)&Wh_h16,   (void*)&W_sT,
      (void*)&WcatT,    (void*)&Wb,        (void*)&A64,      (void*)&attn16,
      (void*)&p_gen_g,  (void*)&part,      (void*)&covloss_b,(void*)&ctrl,
      (void*)&dout};
  hipError_t e = hipLaunchCooperativeKernel((const void*)mega, dim3(NBLK),
                                            dim3(1024), kargs, 0, stream);
  if (e != hipSuccess) {
    hipLaunchKernelGGL(mega, dim3(NBLK), dim3(1024), 0, stream, tgt, hidden,
                       cell, enc, src_lens, embedding, w_c, v_vec, b_attn,
                       b_ih, b_hh, W_pg, b_pg, b_out, Wh_h16, W_sT, WcatT, Wb,
                       A64, attn16, p_gen_g, part, covloss_b, ctrl, dout);
  }
  post_norm<<<CB * CTM1, 256, 0, stream>>>(part, p_gen_g, dout);
  post_tail<<<CB, 256, 0, stream>>>(attn16, p_gen_g, copy_idx, covloss_b,
                                    dout);
}

// Round 11
// 2003.327 us; speedup vs baseline: 3.8727x; 1.3346x over previous
//
#include <hip/hip_runtime.h>
#include <math.h>

// Problem constants
#define CB 16
#define CS 400
#define CT 51
#define CTM1 50
#define CV 50000
#define CE 128
#define CH 256
#define CMAXOOV 50
#define CEXT (CV + CMAXOOV)
#define CX 640             // E + H + H  (x = [emb|ctx|h])
#define NST 16             // state blocks
#define NGT 16             // gate blocks
#define NWK 223            // vocab worker blocks (16 waves, 4 tiles each)
#define NBLK 256           // 16 state + 16 gate + 1 agg + 223 workers
#define NTILE 782          // ceil(V/64)

typedef __attribute__((ext_vector_type(4))) float f32x4;
typedef __attribute__((ext_vector_type(8))) short short8;
typedef unsigned int U32;
typedef unsigned long long U64;

__device__ __forceinline__ float wave_sum(float x) {
#pragma unroll
  for (int o = 32; o > 0; o >>= 1) x += __shfl_xor(x, o);
  return x;
}
__device__ __forceinline__ float sigm(float x) {
  return 1.f / (1.f + __expf(-x));
}
__device__ __forceinline__ float ftanh(float x) {
  x = fminf(fmaxf(x, -15.f), 15.f);
  float e = __expf(2.f * x);
  return (e - 1.f) / (e + 1.f);
}
__device__ __forceinline__ unsigned short f2bf(float f) {
  union { float f; U32 u; } x;
  x.f = f;
  U32 r = x.u + 0x7FFFu + ((x.u >> 16) & 1u);  // RNE
  return (unsigned short)(r >> 16);
}
__device__ __forceinline__ float bf2f(unsigned short u) {
  return __uint_as_float(((U32)u) << 16);
}
__device__ __forceinline__ U64 pack4(float a, float b, float c, float d) {
  return (U64)f2bf(a) | ((U64)f2bf(b) << 16) | ((U64)f2bf(c) << 32) |
         ((U64)f2bf(d) << 48);
}
// uncached (device-coherent) ops — flags + producer-side publishes ONLY
__device__ __forceinline__ U32 ald32(const U32* p) {
  return __hip_atomic_load(p, __ATOMIC_RELAXED, __HIP_MEMORY_SCOPE_AGENT);
}
__device__ __forceinline__ void ast32(U32* p, U32 v) {
  __hip_atomic_store(p, v, __ATOMIC_RELAXED, __HIP_MEMORY_SCOPE_AGENT);
}
__device__ __forceinline__ void ast64(U64* p, U64 v) {
  __hip_atomic_store(p, v, __ATOMIC_RELAXED, __HIP_MEMORY_SCOPE_AGENT);
}
#define VM0 asm volatile("s_waitcnt vmcnt(0)" ::: "memory")

// ---------------------------------------------------------------------------
// One-time weight prep
// ---------------------------------------------------------------------------
__global__ __launch_bounds__(256) void pw_convert(
    const float* __restrict__ W, unsigned short* __restrict__ Wb) {
  size_t i = ((size_t)blockIdx.x * 256 + threadIdx.x) * 8;
  float4 a = *(const float4*)(W + i);
  float4 b = *(const float4*)(W + i + 4);
  short8 o;
  o[0] = (short)f2bf(a.x); o[1] = (short)f2bf(a.y);
  o[2] = (short)f2bf(a.z); o[3] = (short)f2bf(a.w);
  o[4] = (short)f2bf(b.x); o[5] = (short)f2bf(b.y);
  o[6] = (short)f2bf(b.z); o[7] = (short)f2bf(b.w);
  *(short8*)(Wb + i) = o;
}

// Wcat[j][k] bf16 row-major [1024][640]: k<384 -> W_ih[j][k], else W_hh.
__global__ __launch_bounds__(256) void pw_cat(
    const float* __restrict__ W_ih, const float* __restrict__ W_hh,
    unsigned short* __restrict__ Wcat) {
  int t8 = blockIdx.x * 256 + threadIdx.x;  // 81920 short8
  int j = t8 / 80, k8 = t8 % 80;
  short8 o;
#pragma unroll
  for (int i = 0; i < 8; ++i) {
    int k = k8 * 8 + i;
    float v = (k < CE + CH) ? W_ih[(size_t)j * (CE + CH) + k]
                            : W_hh[(size_t)j * CH + (k - (CE + CH))];
    o[i] = (short)f2bf(v);
  }
  *(short8*)(Wcat + (size_t)t8 * 8) = o;
}

// fp32 256x256 transpose (for p0's W_hT)
__global__ __launch_bounds__(256) void pw_t256(const float* __restrict__ in,
                                               float* __restrict__ out) {
  int j = blockIdx.x, k = threadIdx.x;
  out[j * CH + k] = in[k * CH + j];
}

// bf16 transposed W_s: W_sT16[j][k] = bf16(W_s[k][j])
__global__ __launch_bounds__(256) void pw_t256_bf16(
    const float* __restrict__ in, unsigned short* __restrict__ out) {
  int j = blockIdx.x, k = threadIdx.x;
  out[j * CH + k] = f2bf(in[k * CH + j]);
}

// generic fp32 -> bf16 (enc16): grid*256*8 elems
__global__ __launch_bounds__(256) void pw_cvt16(
    const float* __restrict__ in, unsigned short* __restrict__ out) {
  size_t i = ((size_t)blockIdx.x * 256 + threadIdx.x) * 8;
  float4 a = *(const float4*)(in + i);
  float4 b = *(const float4*)(in + i + 4);
  short8 o;
  o[0] = (short)f2bf(a.x); o[1] = (short)f2bf(a.y);
  o[2] = (short)f2bf(a.z); o[3] = (short)f2bf(a.w);
  o[4] = (short)f2bf(b.x); o[5] = (short)f2bf(b.y);
  o[6] = (short)f2bf(b.z); o[7] = (short)f2bf(b.w);
  *(short8*)(out + i) = o;
}

// ---------------------------------------------------------------------------
// P0: Wh_h16 (bf16) = enc @ W_h^T (coalesced via W_hT); copy_idx.
// ---------------------------------------------------------------------------
__global__ __launch_bounds__(256) void p0_precompute(
    const float* __restrict__ enc, const float* __restrict__ W_hT,
    const int* __restrict__ src_ids, const int* __restrict__ src_oov,
    unsigned short* __restrict__ Wh_h16, int* __restrict__ copy_idx) {
  const int row0 = blockIdx.x * 8, tid = threadIdx.x;
  __shared__ float erT[CH * 8];
#pragma unroll
  for (int i = 0; i < 8; ++i) {
    int idx = tid + i * 256;
    int r = idx >> 8, j = idx & 255;
    erT[j * 8 + r] = enc[(size_t)row0 * CH + idx];
  }
  if (tid < 8) {
    int row = row0 + tid;
    int ov = src_oov[row];
    copy_idx[row] = (ov >= 0) ? (CV + ov) : src_ids[row];
  }
  __syncthreads();
  float acc[8] = {0, 0, 0, 0, 0, 0, 0, 0};
#pragma unroll 4
  for (int j = 0; j < CH; ++j) {
    float w = W_hT[j * CH + tid];
    float4 e0 = *(const float4*)&erT[j * 8];
    float4 e1 = *(const float4*)&erT[j * 8 + 4];
    acc[0] += e0.x * w; acc[1] += e0.y * w; acc[2] += e0.z * w; acc[3] += e0.w * w;
    acc[4] += e1.x * w; acc[5] += e1.y * w; acc[6] += e1.z * w; acc[7] += e1.w * w;
  }
#pragma unroll
  for (int r = 0; r < 8; ++r)
    Wh_h16[(size_t)(row0 + r) * CH + tid] = f2bf(acc[r]);
}

// ---------------------------------------------------------------------------
// Z: zero control words + rowsum partials (every call: replay-safe).
// ctrl: arrive@0 (16x16) | release@256 (64x16) | xrdy@1280 (16x16)
//       grdy@1536 (16x16)
// ---------------------------------------------------------------------------
__global__ __launch_bounds__(256) void z_init(U32* __restrict__ ctrl,
                                              float* __restrict__ part) {
  int tid = blockIdx.x * 256 + threadIdx.x;
  if (tid < 2048) ctrl[tid] = 0u;
  for (int i = tid; i < CTM1 * CB * 64; i += 256 * 64) part[i] = 0.f;
}

// ---------------------------------------------------------------------------
// MEGA: 16 state + 16 gate + 1 aggregator + 223 vocab workers.
// Gates = MFMA GEMM sliced over gate blocks (kills the 16x WcatT stream).
// ---------------------------------------------------------------------------
__global__ __launch_bounds__(1024, 4) void mega(
    const int* __restrict__ tgt, const float* __restrict__ hidden,
    const float* __restrict__ cell, const int* __restrict__ src_lens,
    const float* __restrict__ embedding, const float* __restrict__ w_c,
    const float* __restrict__ v_vec, const float* __restrict__ b_attn,
    const float* __restrict__ b_ih, const float* __restrict__ b_hh,
    const float* __restrict__ W_pg, const float* __restrict__ b_pg,
    const float* __restrict__ b_out,
    const unsigned short* __restrict__ Wh_h16,
    const unsigned short* __restrict__ enc16,
    const unsigned short* __restrict__ W_sT16,
    const unsigned short* __restrict__ Wcat,
    const unsigned short* __restrict__ Wb, U64* __restrict__ A64,
    U64* __restrict__ x64, U64* __restrict__ g64,
    unsigned short* __restrict__ attn16, float* __restrict__ p_gen_g,
    float* __restrict__ part, float* __restrict__ covloss_b,
    U32* __restrict__ ctrl, float* __restrict__ dout) {
  const int bid = blockIdx.x, tid = threadIdx.x;
  const int lane = tid & 63, wv = tid >> 6;  // 16 waves
  U32* arrive = ctrl;           // state phase-C flags (worker release src)
  U32* release = ctrl + 256;    // 64 worker replicas
  U32* xrdy = ctrl + 1280;      // state phase-A flags (x published)
  U32* grdy = ctrl + 1536;      // gate-block flags (gates published)

  __shared__ __align__(16) U64 sh_big[2592];  // worker A / gate x staging
  __shared__ float cov_s[CS];
  __shared__ float a_s[CS];
  __shared__ __align__(16) float h_cur[CH];
  __shared__ float hws_s[CH];
  __shared__ __align__(16) float ctx_s[CH];
  __shared__ float emb_s[CE];
  __shared__ float pctx[4 * CH];   // 4-group partials (ctx / hWs)
  __shared__ float gsl[CB][64];    // gate block: gates slice staging
  __shared__ float red[16];
  __shared__ float stat[4];
  __shared__ float prs[16][16];

  if (bid < NST) {
    // ================= STATE LANE (batch b), 16 waves =================
    const int b = bid;
    const int len = src_lens[b];
    const float ba = b_attn[0];
    const int k4 = lane * 4;
    const float4 wc4 = *(const float4*)(w_c + k4);
    const float4 vv4 = *(const float4*)(v_vec + k4);
    const float bias_reg = b_ih[tid] + b_hh[tid];  // bias for gate col tid
    const int kg = tid & 255, grp = tid >> 8;      // 4 groups of 256
    float covl = 0.f;
    float c_reg = (tid < CH) ? cell[b * CH + tid] : 0.f;

    if (tid < CS) cov_s[tid] = 0.f;
    if (tid < CH) h_cur[tid] = hidden[b * CH + tid];
    __syncthreads();
    {  // hWs init (bf16 W_sT16)
      float acc = 0.f;
#pragma unroll 8
      for (int j = grp * 64; j < grp * 64 + 64; ++j)
        acc += h_cur[j] * bf2f(W_sT16[j * CH + kg]);
      pctx[grp * CH + kg] = acc;
    }
    // x64[0] h part
    if (tid < 64)
      ast64(&x64[b * 160 + 96 + tid],
            pack4(h_cur[4 * tid], h_cur[4 * tid + 1], h_cur[4 * tid + 2],
                  h_cur[4 * tid + 3]));
    __syncthreads();
    if (tid < CH)
      hws_s[tid] = pctx[tid] + pctx[CH + tid] + pctx[2 * CH + tid] +
                   pctx[3 * CH + tid];
    __syncthreads();

    for (int t = 0; t < CTM1; ++t) {
      // ---- phase A: coverage, scores, softmax, ctx, publish x ----
      if (t > 0) {
        if (tid < CS) {
          float a = a_s[tid], cv = cov_s[tid];
          covl += fminf(a, cv);
          cov_s[tid] = cv + a;
        }
        __syncthreads();
      }
      const int tok = tgt[b * CT + t];
      if (tid < CE) emb_s[tid] = embedding[(size_t)tok * CE + tid];
      float ps = 0.f;
      for (int s = wv; s < CS; s += 16) {
        float cv = cov_s[s];
        U64 wq = *(const U64*)(Wh_h16 + ((size_t)(b * CS + s)) * CH + k4);
        float p =
            ftanh(bf2f((unsigned short)wq) + hws_s[k4] + cv * wc4.x + ba) *
                vv4.x +
            ftanh(bf2f((unsigned short)(wq >> 16)) + hws_s[k4 + 1] +
                  cv * wc4.y + ba) *
                vv4.y +
            ftanh(bf2f((unsigned short)(wq >> 32)) + hws_s[k4 + 2] +
                  cv * wc4.z + ba) *
                vv4.z +
            ftanh(bf2f((unsigned short)(wq >> 48)) + hws_s[k4 + 3] +
                  cv * wc4.w + ba) *
                vv4.w;
        p = wave_sum(p);
        if (lane == 0) {
          float e = (s < len) ? __expf(p) : 0.f;  // |score| <~ 10: safe
          a_s[s] = e;
          ps += e;
        }
      }
      if (lane == 0) red[wv] = ps;
      __syncthreads();
      if (tid == 0) {
        float s2 = 0.f;
#pragma unroll
        for (int i = 0; i < 16; ++i) s2 += red[i];
        stat[0] = 1.f / s2;
      }
      __syncthreads();
      const float inv = stat[0];
      if (tid < CS) {
        float a = a_s[tid] * inv;
        a_s[tid] = a;
        attn16[((size_t)t * CB + b) * CS + tid] = f2bf(a);
      }
      __syncthreads();
      {  // ctx partial (enc16): group grp handles s in [grp*100, +100)
        float pc = 0.f;
        const unsigned short* er =
            enc16 + ((size_t)(b * CS + grp * 100)) * CH + kg;
#pragma unroll 10
        for (int i = 0; i < 100; ++i)
          pc += a_s[grp * 100 + i] * bf2f(er[(size_t)i * CH]);
        pctx[grp * CH + kg] = pc;
      }
      __syncthreads();
      if (tid < CH)
        ctx_s[tid] = pctx[tid] + pctx[CH + tid] + pctx[2 * CH + tid] +
                     pctx[3 * CH + tid];
      __syncthreads();
      // publish x row (emb: u64 0..31, ctx: 32..95) + A64 ctx half
      {
        U64* xr = x64 + (size_t)t * 2560 + b * 160;
        if (tid < 32) {
          ast64(&xr[tid], pack4(emb_s[4 * tid], emb_s[4 * tid + 1],
                                emb_s[4 * tid + 2], emb_s[4 * tid + 3]));
        } else if (tid < 96) {
          int i = tid - 32;
          ast64(&xr[32 + i], pack4(ctx_s[4 * i], ctx_s[4 * i + 1],
                                   ctx_s[4 * i + 2], ctx_s[4 * i + 3]));
        } else if (tid < 160) {
          int i = tid - 96;
          ast64(&A64[(size_t)t * 2048 + b * 128 + 64 + i],
                pack4(ctx_s[4 * i], ctx_s[4 * i + 1], ctx_s[4 * i + 2],
                      ctx_s[4 * i + 3]));
        }
      }
      VM0;
      __syncthreads();
      if (tid == 0) ast32(&xrdy[b * 16], (U32)(t + 1));
      // ---- wait gates ----
      if (wv == 0) {
        int gg = 0;
        while (gg < (1 << 20)) {
          U32 v = (lane < NGT) ? ald32(&grdy[lane * 16]) : (U32)(t + 1);
          if (__all(v >= (U32)(t + 1))) break;
          __builtin_amdgcn_s_sleep(4);
          ++gg;
        }
      }
      __syncthreads();
      // ---- phase C: cell update, publish h, hWs(next), p_gen ----
      if (tid < CH) {
        const float* gr = (const float*)(g64 + (size_t)t * 8192) + b * 1024;
        float gi = gr[tid] + bias_reg;
        float gf = gr[CH + tid] + b_ih[CH + tid] + b_hh[CH + tid];
        float gg2 = gr[2 * CH + tid] + b_ih[2 * CH + tid] + b_hh[2 * CH + tid];
        float go = gr[3 * CH + tid] + b_ih[3 * CH + tid] + b_hh[3 * CH + tid];
        float cn = sigm(gf) * c_reg + sigm(gi) * ftanh(gg2);
        c_reg = cn;
        h_cur[tid] = sigm(go) * ftanh(cn);
      }
      __syncthreads();
      if (tid < 64) {  // A64 h half
        ast64(&A64[(size_t)t * 2048 + b * 128 + tid],
              pack4(h_cur[4 * tid], h_cur[4 * tid + 1], h_cur[4 * tid + 2],
                    h_cur[4 * tid + 3]));
      } else if (tid < 128 && t + 1 < CTM1) {  // x64[t+1] h part
        int i = tid - 64;
        ast64(&x64[(size_t)(t + 1) * 2560 + b * 160 + 96 + i],
              pack4(h_cur[4 * i], h_cur[4 * i + 1], h_cur[4 * i + 2],
                    h_cur[4 * i + 3]));
      }
      VM0;
      __syncthreads();
      if (tid == 0) ast32(&arrive[b * 16], (U32)(t + 1));
      // off-critical-path: hWs(next) + p_gen
      {
        float acc = 0.f;
#pragma unroll 8
        for (int j = grp * 64; j < grp * 64 + 64; ++j)
          acc += h_cur[j] * bf2f(W_sT16[j * CH + kg]);
        pctx[grp * CH + kg] = acc;
      }
      __syncthreads();
      if (tid < CH)
        hws_s[tid] = pctx[tid] + pctx[CH + tid] + pctx[2 * CH + tid] +
                     pctx[3 * CH + tid];
      {
        float z = 0.f;
        if (tid < CH)
          z = h_cur[tid] * W_pg[tid] + ctx_s[tid] * W_pg[CH + tid];
        if (tid < CE) z += emb_s[tid] * W_pg[2 * CH + tid];
        z = wave_sum(z);
        if (lane == 0) red[wv] = z;
        __syncthreads();
        if (tid == 0) {
          float s2 = 0.f;
#pragma unroll
          for (int i = 0; i < 16; ++i) s2 += red[i];
          p_gen_g[t * CB + b] = sigm(s2 + b_pg[0]);
        }
      }
      __syncthreads();
    }
    // tail
    if (tid < CS) covl += fminf(a_s[tid], cov_s[tid]);
    covl = wave_sum(covl);
    if (lane == 0) red[wv] = covl;
    __syncthreads();
    if (tid == 0) {
      float s2 = 0.f;
#pragma unroll
      for (int i = 0; i < 16; ++i) s2 += red[i];
      covloss_b[b] = s2;
    }
    if (tid < CH) {
      const size_t D0 = (size_t)CB * CTM1 * CEXT;
      dout[D0 + b * CH + tid] = h_cur[tid];
      dout[D0 + CB * CH + b * CH + tid] = c_reg;
    }
  } else if (bid < NST + NGT) {
    // ================= GATE BLOCKS: cols g*64..+63, all batches ==========
    const int g = bid - NST;
    const int n0 = g * 64;
    const int nn = lane & 15, gq = lane >> 4;
    U64* xl = sh_big;  // [16][81] short8 == row stride 162 u64
    const short8* x8 = (const short8*)sh_big;
    for (int t = 0; t < CTM1; ++t) {
      if (wv == 0) {  // wait all x rows
        int gg = 0;
        while (gg < (1 << 20)) {
          U32 v = (lane < NST) ? ald32(&xrdy[lane * 16]) : (U32)(t + 1);
          if (__all(v >= (U32)(t + 1))) break;
          __builtin_amdgcn_s_sleep(4);
          ++gg;
        }
      }
      __syncthreads();
      {  // stage x (cached reads; first touch after flag)
        const U64* src = x64 + (size_t)t * 2560;
        for (int idx = tid; idx < 2560; idx += 1024) {
          int row = idx / 160, col = idx - row * 160;
          xl[row * 162 + col] = src[idx];
        }
      }
      __syncthreads();
      if (wv < 4) {
        const int ncol = n0 + wv * 16 + nn;
        const short8* bp = (const short8*)Wcat + (size_t)ncol * 80;
        short8 af[20];
#pragma unroll
        for (int kt = 0; kt < 20; ++kt) af[kt] = x8[nn * 81 + kt * 4 + gq];
        f32x4 acc = {0.f, 0.f, 0.f, 0.f};
#pragma unroll
        for (int kt = 0; kt < 20; ++kt)
          acc = __builtin_amdgcn_mfma_f32_16x16x32_bf16(af[kt], bp[kt * 4 + gq],
                                                        acc, 0, 0, 0);
#pragma unroll
        for (int r = 0; r < 4; ++r) gsl[gq * 4 + r][wv * 16 + nn] = acc[r];
      }
      __syncthreads();
      if (tid < 512) {  // publish fp32 gates slice (UC, u64-packed)
        int b = tid >> 5, i = tid & 31;
        U64 w = (U64)__float_as_uint(gsl[b][2 * i]) |
                ((U64)__float_as_uint(gsl[b][2 * i + 1]) << 32);
        ast64(&g64[(size_t)t * 8192 + b * 512 + (n0 >> 1) + i], w);
      }
      VM0;
      __syncthreads();
      if (tid == 0) ast32(&grdy[g * 16], (U32)(t + 1));
    }
  } else if (bid == NST + NGT) {
    // ===================== AGGREGATOR (1 block) ==========================
    for (int t = 0; t < CTM1; ++t) {
      if (wv == 0) {
        int gg = 0;
        while (gg < (1 << 20)) {
          U32 v = (lane < NST) ? ald32(&arrive[lane * 16]) : (U32)(t + 1);
          if (__all(v >= (U32)(t + 1))) break;
          __builtin_amdgcn_s_sleep(8);
          ++gg;
        }
      }
      __syncthreads();
      if (tid < 64) ast32(&release[tid * 16], (U32)(t + 1));
      __syncthreads();
    }
  } else {
    // ============ VOCAB WORKERS (223 blocks, 16 waves, 4 tiles) ==========
    const int vb = bid - NST - NGT - 1;
    const int rep = vb & 63;
    const int nn = lane & 15, g = lane >> 4;
    const int t4 = (wv >> 2) * NWK + vb;     // this wave's tile
    const int v = t4 * 64 + (wv & 3) * 16 + nn;
    const bool live = (t4 < NTILE) && (v < CV);
    const int vc = live ? v : CV - 1;
    U64* a64l = sh_big;  // [16][130] u64
    const short8* lds8 = (const short8*)sh_big;
    const short8* bp = (const short8*)Wb + (size_t)vc * 64;  // cached
    const float bo = live ? b_out[v] : 0.f;
    for (int t = 0; t < CTM1; ++t) {
      if (tid == 0) {
        int gg = 0;
        while (ald32(&release[rep * 16]) < (U32)(t + 1) && ++gg < (1 << 18))
          __builtin_amdgcn_s_sleep(32);
      }
      __syncthreads();
      {  // stage A slab cached
        const U64* src = A64 + (size_t)t * 2048;
#pragma unroll
        for (int i = 0; i < 2; ++i) {
          int idx = tid + i * 1024;
          int row = idx >> 7, col = idx & 127;
          a64l[row * 130 + col] = src[idx];
        }
      }
      __syncthreads();
      short8 af[16];
#pragma unroll
      for (int kt = 0; kt < 16; ++kt) af[kt] = lds8[nn * 65 + kt * 4 + g];
      f32x4 acc = {0.f, 0.f, 0.f, 0.f};
#pragma unroll
      for (int kt = 0; kt < 16; ++kt)
        acc = __builtin_amdgcn_mfma_f32_16x16x32_bf16(af[kt], bp[kt * 4 + g],
                                                      acc, 0, 0, 0);
      float ev[4];
#pragma unroll
      for (int r = 0; r < 4; ++r) {
        float e = live ? __expf(acc[r] + bo) : 0.f;
        if (live) dout[((size_t)((g * 4 + r) * CTM1 + t)) * CEXT + v] = e;
#pragma unroll
        for (int o = 1; o < 16; o <<= 1) e += __shfl_xor(e, o);
        ev[r] = e;
      }
      if (nn == 0) {
#pragma unroll
        for (int r = 0; r < 4; ++r) prs[wv][g * 4 + r] = ev[r];
      }
      __syncthreads();
      if (tid < 16) {
        float s = 0.f;
#pragma unroll
        for (int w = 0; w < 16; ++w) s += prs[w][tid];
        atomicAdd(&part[((size_t)t * CB + tid) * 64 + rep], s);
      }
      __syncthreads();
    }
  }
}

// ---------------------------------------------------------------------------
// POST 1: per (b,t) row: reduce 64 rowsum partials, normalize + zero pads.
// ---------------------------------------------------------------------------
__global__ __launch_bounds__(256) void post_norm(
    const float* __restrict__ part, const float* __restrict__ p_gen_g,
    float* __restrict__ dout) {
  const int R = blockIdx.x;
  const int b = R / CTM1, t = R % CTM1;
  const int tid = threadIdx.x;
  __shared__ float stat;
  float s = (tid < 64) ? part[((size_t)t * CB + b) * 64 + tid] : 0.f;
  s = wave_sum(s);
  if (tid == 0) stat = p_gen_g[t * CB + b] / s;
  __syncthreads();
  float inv = stat;
  float* drow = dout + (size_t)R * CEXT;
  for (int v = tid; v < CEXT; v += 256)
    drow[v] = (v < CV) ? drow[v] * inv : 0.f;
}

// ---------------------------------------------------------------------------
// POST 2: copy-dist scatter for all t + coverage_loss. grid = 16.
// ---------------------------------------------------------------------------
__global__ __launch_bounds__(256) void post_tail(
    const unsigned short* __restrict__ attn16,
    const float* __restrict__ p_gen_g, const int* __restrict__ copy_idx,
    const float* __restrict__ covloss_b, float* __restrict__ dout) {
  const int b = blockIdx.x, tid = threadIdx.x;
  for (int t = 0; t < CTM1; ++t) {
    float pg1 = 1.f - p_gen_g[t * CB + b];
    const unsigned short* ar = attn16 + ((size_t)t * CB + b) * CS;
    float* drow = dout + ((size_t)(b * CTM1 + t)) * CEXT;
    for (int s = tid; s < CS; s += 256)
      atomicAdd(drow + copy_idx[b * CS + s], pg1 * bf2f(ar[s]));
  }
  if (b == 0 && tid == 0) {
    const size_t D0 = (size_t)CB * CTM1 * CEXT;
    float s = 0.f;
    for (int i = 0; i < CB; ++i) s += covloss_b[i];
    dout[D0 + 2 * CB * CH] = s / (float)(CTM1 * CB);
  }
}

// ---------------------------------------------------------------------------
extern "C" void kernel_launch(void* const* d_in, const int* in_sizes, int n_in,
                              void* d_out, int out_size, void* d_ws,
                              size_t ws_size, hipStream_t stream) {
  const int* tgt = (const int*)d_in[0];
  const float* hidden = (const float*)d_in[1];
  const float* cell = (const float*)d_in[2];
  const float* enc = (const float*)d_in[3];
  const int* src_lens = (const int*)d_in[4];
  const int* src_ids = (const int*)d_in[5];
  const int* src_oov = (const int*)d_in[6];
  const float* embedding = (const float*)d_in[7];
  const float* W_h = (const float*)d_in[8];
  const float* W_s = (const float*)d_in[9];
  const float* w_c = (const float*)d_in[10];
  const float* v_vec = (const float*)d_in[11];
  const float* b_attn = (const float*)d_in[12];
  const float* W_ih = (const float*)d_in[13];
  const float* W_hh = (const float*)d_in[14];
  const float* b_ih = (const float*)d_in[15];
  const float* b_hh = (const float*)d_in[16];
  const float* W_pg = (const float*)d_in[17];
  const float* b_pg = (const float*)d_in[18];
  const float* W_out = (const float*)d_in[19];
  const float* b_out = (const float*)d_in[20];
  float* dout = (float*)d_out;

  // workspace layout (f32/int region first — word count even before u64s)
  float* ws = (float*)d_ws;
  float* W_hT = ws;                                  // 65,536 f
  float* p_gen_g = W_hT + CH * CH;                   // 800 f
  float* part = p_gen_g + CTM1 * CB;                 // 51,200 f
  float* covloss_b = part + CTM1 * CB * 64;          // 16 f
  int* copy_idx = (int*)(covloss_b + 16);            // 6,400 i
  U32* ctrl = (U32*)(copy_idx + CB * CS);            // 2,048 u32
  U64* A64 = (U64*)(ctrl + 2048);                    // 102,400 u64
  U64* x64 = A64 + (size_t)CTM1 * 2048;              // 51*2560 u64
  U64* g64 = x64 + (size_t)51 * 2560;                // 50*8192 u64
  unsigned short* attn16 =
      (unsigned short*)(g64 + (size_t)CTM1 * 8192);  // 320,000 sh
  unsigned short* Wh_h16 = attn16 + (size_t)CTM1 * CB * CS;  // 1,638,400 sh
  unsigned short* enc16 = Wh_h16 + (size_t)CB * CS * CH;     // 1,638,400 sh
  unsigned short* W_sT16 = enc16 + (size_t)CB * CS * CH;     // 65,536 sh
  unsigned short* Wcat = W_sT16 + CH * CH;           // 655,360 sh
  unsigned short* Wb = Wcat + (size_t)(4 * CH) * CX; // 25,600,000 sh

  z_init<<<64, 256, 0, stream>>>(ctrl, part);
  pw_convert<<<(CV * 2 * CH) / (256 * 8), 256, 0, stream>>>(W_out, Wb);
  pw_cat<<<((4 * CH) * CX / 8) / 256, 256, 0, stream>>>(W_ih, W_hh, Wcat);
  pw_t256<<<CH, CH, 0, stream>>>(W_h, W_hT);
  pw_t256_bf16<<<CH, CH, 0, stream>>>(W_s, W_sT16);
  pw_cvt16<<<(CB * CS * CH) / (256 * 8), 256, 0, stream>>>(enc, enc16);
  p0_precompute<<<CB * CS / 8, 256, 0, stream>>>(enc, W_hT, src_ids, src_oov,
                                                 Wh_h16, copy_idx);

  void* kargs[] = {
      (void*)&tgt,      (void*)&hidden,    (void*)&cell,    (void*)&src_lens,
      (void*)&embedding,(void*)&w_c,       (void*)&v_vec,   (void*)&b_attn,
      (void*)&b_ih,     (void*)&b_hh,      (void*)&W_pg,    (void*)&b_pg,
      (void*)&b_out,    (void*)&Wh_h16,    (void*)&enc16,   (void*)&W_sT16,
      (void*)&Wcat,     (void*)&Wb,        (void*)&A64,     (void*)&x64,
      (void*)&g64,      (void*)&attn16,    (void*)&p_gen_g, (void*)&part,
      (void*)&covloss_b,(void*)&ctrl,      (void*)&dout};
  hipError_t e = hipLaunchCooperativeKernel((const void*)mega, dim3(NBLK),
                                            dim3(1024), kargs, 0, stream);
  if (e != hipSuccess) {
    hipLaunchKernelGGL(mega, dim3(NBLK), dim3(1024), 0, stream, tgt, hidden,
                       cell, src_lens, embedding, w_c, v_vec, b_attn, b_ih,
                       b_hh, W_pg, b_pg, b_out, Wh_h16, enc16, W_sT16, Wcat,
                       Wb, A64, x64, g64, attn16, p_gen_g, part, covloss_b,
                       ctrl, dout);
  }
  post_norm<<<CB * CTM1, 256, 0, stream>>>(part, p_gen_g, dout);
  post_tail<<<CB, 256, 0, stream>>>(attn16, p_gen_g, copy_idx, covloss_b,
                                    dout);
}

// Round 12
// 1862.302 us; speedup vs baseline: 4.1659x; 1.0757x over previous
//
#include <hip/hip_runtime.h>
#include <math.h>

// Problem constants
#define CB 16
#define CS 400
#define CT 51
#define CTM1 50
#define CV 50000
#define CE 128
#define CH 256
#define CMAXOOV 50
#define CEXT (CV + CMAXOOV)
#define CX 640             // gate GEMM K = [emb(128)|ctx(256)|h(256)]
#define NST 16             // state blocks
#define NGT 16             // gate blocks
#define NWK 223            // vocab worker blocks
#define NBLK 256           // 16 state + 16 gate + 1 agg + 223 workers
#define NTILE 782          // ceil(V/64)

typedef __attribute__((ext_vector_type(4))) float f32x4;
typedef __attribute__((ext_vector_type(8))) short short8;
typedef unsigned int U32;
typedef unsigned long long U64;

__device__ __forceinline__ float wave_sum(float x) {
#pragma unroll
  for (int o = 32; o > 0; o >>= 1) x += __shfl_xor(x, o);
  return x;
}
__device__ __forceinline__ float sigm(float x) {
  return 1.f / (1.f + __expf(-x));
}
__device__ __forceinline__ float ftanh(float x) {
  x = fminf(fmaxf(x, -15.f), 15.f);
  float e = __expf(2.f * x);
  return (e - 1.f) / (e + 1.f);
}
__device__ __forceinline__ unsigned short f2bf(float f) {
  union { float f; U32 u; } x;
  x.f = f;
  U32 r = x.u + 0x7FFFu + ((x.u >> 16) & 1u);  // RNE
  return (unsigned short)(r >> 16);
}
__device__ __forceinline__ float bf2f(unsigned short u) {
  return __uint_as_float(((U32)u) << 16);
}
__device__ __forceinline__ U64 pack4(float a, float b, float c, float d) {
  return (U64)f2bf(a) | ((U64)f2bf(b) << 16) | ((U64)f2bf(c) << 32) |
         ((U64)f2bf(d) << 48);
}
// uncached (device-coherent) ops — flags + producer-side publishes ONLY
__device__ __forceinline__ U32 ald32(const U32* p) {
  return __hip_atomic_load(p, __ATOMIC_RELAXED, __HIP_MEMORY_SCOPE_AGENT);
}
__device__ __forceinline__ void ast32(U32* p, U32 v) {
  __hip_atomic_store(p, v, __ATOMIC_RELAXED, __HIP_MEMORY_SCOPE_AGENT);
}
__device__ __forceinline__ void ast64(U64* p, U64 v) {
  __hip_atomic_store(p, v, __ATOMIC_RELAXED, __HIP_MEMORY_SCOPE_AGENT);
}
#define VM0 asm volatile("s_waitcnt vmcnt(0)" ::: "memory")

// ---------------------------------------------------------------------------
// One-time weight prep
// ---------------------------------------------------------------------------
__global__ __launch_bounds__(256) void pw_convert(
    const float* __restrict__ W, unsigned short* __restrict__ Wb) {
  size_t i = ((size_t)blockIdx.x * 256 + threadIdx.x) * 8;
  float4 a = *(const float4*)(W + i);
  float4 b = *(const float4*)(W + i + 4);
  short8 o;
  o[0] = (short)f2bf(a.x); o[1] = (short)f2bf(a.y);
  o[2] = (short)f2bf(a.z); o[3] = (short)f2bf(a.w);
  o[4] = (short)f2bf(b.x); o[5] = (short)f2bf(b.y);
  o[6] = (short)f2bf(b.z); o[7] = (short)f2bf(b.w);
  *(short8*)(Wb + i) = o;
}

// Wcat[j][k] bf16 row-major [1024][640]: k<384 -> W_ih[j][k], else W_hh.
__global__ __launch_bounds__(256) void pw_cat(
    const float* __restrict__ W_ih, const float* __restrict__ W_hh,
    unsigned short* __restrict__ Wcat) {
  int t8 = blockIdx.x * 256 + threadIdx.x;  // 81920 short8
  int j = t8 / 80, k8 = t8 % 80;
  short8 o;
#pragma unroll
  for (int i = 0; i < 8; ++i) {
    int k = k8 * 8 + i;
    float v = (k < CE + CH) ? W_ih[(size_t)j * (CE + CH) + k]
                            : W_hh[(size_t)j * CH + (k - (CE + CH))];
    o[i] = (short)f2bf(v);
  }
  *(short8*)(Wcat + (size_t)t8 * 8) = o;
}

// fp32 256x256 transpose (for p0's W_hT)
__global__ __launch_bounds__(256) void pw_t256(const float* __restrict__ in,
                                               float* __restrict__ out) {
  int j = blockIdx.x, k = threadIdx.x;
  out[j * CH + k] = in[k * CH + j];
}

// bf16 transposed W_s: W_sT16[j][k] = bf16(W_s[k][j])
__global__ __launch_bounds__(256) void pw_t256_bf16(
    const float* __restrict__ in, unsigned short* __restrict__ out) {
  int j = blockIdx.x, k = threadIdx.x;
  out[j * CH + k] = f2bf(in[k * CH + j]);
}

// generic fp32 -> bf16 (enc16)
__global__ __launch_bounds__(256) void pw_cvt16(
    const float* __restrict__ in, unsigned short* __restrict__ out) {
  size_t i = ((size_t)blockIdx.x * 256 + threadIdx.x) * 8;
  float4 a = *(const float4*)(in + i);
  float4 b = *(const float4*)(in + i + 4);
  short8 o;
  o[0] = (short)f2bf(a.x); o[1] = (short)f2bf(a.y);
  o[2] = (short)f2bf(a.z); o[3] = (short)f2bf(a.w);
  o[4] = (short)f2bf(b.x); o[5] = (short)f2bf(b.y);
  o[6] = (short)f2bf(b.z); o[7] = (short)f2bf(b.w);
  *(short8*)(out + i) = o;
}

// ---------------------------------------------------------------------------
// P0: Wh_h16 (bf16) = enc @ W_h^T (coalesced via W_hT); copy_idx.
// ---------------------------------------------------------------------------
__global__ __launch_bounds__(256) void p0_precompute(
    const float* __restrict__ enc, const float* __restrict__ W_hT,
    const int* __restrict__ src_ids, const int* __restrict__ src_oov,
    unsigned short* __restrict__ Wh_h16, int* __restrict__ copy_idx) {
  const int row0 = blockIdx.x * 8, tid = threadIdx.x;
  __shared__ float erT[CH * 8];
#pragma unroll
  for (int i = 0; i < 8; ++i) {
    int idx = tid + i * 256;
    int r = idx >> 8, j = idx & 255;
    erT[j * 8 + r] = enc[(size_t)row0 * CH + idx];
  }
  if (tid < 8) {
    int row = row0 + tid;
    int ov = src_oov[row];
    copy_idx[row] = (ov >= 0) ? (CV + ov) : src_ids[row];
  }
  __syncthreads();
  float acc[8] = {0, 0, 0, 0, 0, 0, 0, 0};
#pragma unroll 4
  for (int j = 0; j < CH; ++j) {
    float w = W_hT[j * CH + tid];
    float4 e0 = *(const float4*)&erT[j * 8];
    float4 e1 = *(const float4*)&erT[j * 8 + 4];
    acc[0] += e0.x * w; acc[1] += e0.y * w; acc[2] += e0.z * w; acc[3] += e0.w * w;
    acc[4] += e1.x * w; acc[5] += e1.y * w; acc[6] += e1.z * w; acc[7] += e1.w * w;
  }
#pragma unroll
  for (int r = 0; r < 8; ++r)
    Wh_h16[(size_t)(row0 + r) * CH + tid] = f2bf(acc[r]);
}

// ---------------------------------------------------------------------------
// Z: zero control words + rowsum partials (every call: replay-safe).
// ctrl: release@256 (64x16) | xrdy@1280 (16x16) | grdy@1536 (16x16)
// ---------------------------------------------------------------------------
__global__ __launch_bounds__(256) void z_init(U32* __restrict__ ctrl,
                                              float* __restrict__ part) {
  int tid = blockIdx.x * 256 + threadIdx.x;
  if (tid < 2048) ctrl[tid] = 0u;
  for (int i = tid; i < CTM1 * CB * 64; i += 256 * 64) part[i] = 0.f;
}

// ---------------------------------------------------------------------------
// MEGA: 16 state + 16 gate (own cell state) + 1 agg + 223 vocab workers.
// Gate K split: emb+h precomputed during state phase A; only ctx-part + cell
// on the critical path.
// ---------------------------------------------------------------------------
__global__ __launch_bounds__(1024, 4) void mega(
    const int* __restrict__ tgt, const float* __restrict__ hidden,
    const float* __restrict__ cell, const int* __restrict__ src_lens,
    const float* __restrict__ embedding, const float* __restrict__ w_c,
    const float* __restrict__ v_vec, const float* __restrict__ b_attn,
    const float* __restrict__ b_ih, const float* __restrict__ b_hh,
    const float* __restrict__ W_pg, const float* __restrict__ b_pg,
    const float* __restrict__ b_out,
    const unsigned short* __restrict__ Wh_h16,
    const unsigned short* __restrict__ enc16,
    const unsigned short* __restrict__ W_sT16,
    const unsigned short* __restrict__ Wcat,
    const unsigned short* __restrict__ Wb, U64* __restrict__ A64,
    float* __restrict__ HexF, unsigned short* __restrict__ attn16,
    float* __restrict__ p_gen_g, float* __restrict__ part,
    float* __restrict__ covloss_b, U32* __restrict__ ctrl,
    float* __restrict__ dout) {
  const int bid = blockIdx.x, tid = threadIdx.x;
  const int lane = tid & 63, wv = tid >> 6;  // 16 waves
  U32* release = ctrl + 256;    // 64 worker replicas
  U32* xrdy = ctrl + 1280;      // state: ctx published
  U32* grdy = ctrl + 1536;      // gate: h slice published

  __shared__ __align__(16) U64 sh_big[2592];  // gate xg / worker A staging
  __shared__ float cov_s[CS];
  __shared__ float a_s[CS];
  __shared__ __align__(16) float h_cur[CH];
  __shared__ float hws_s[CH];
  __shared__ __align__(16) float ctx_s[CH];
  __shared__ float emb_s[CE];
  __shared__ float pctx[4 * CH];
  __shared__ float gsl[4][CB][16];  // gate: [type][b][unit]
  __shared__ int sh_tok[CB];
  __shared__ float red[16];
  __shared__ float stat[4];
  __shared__ float prs[16][16];

  if (bid < NST) {
    // ================= STATE LANE (batch b), 16 waves =================
    const int b = bid;
    const int len = src_lens[b];
    const float ba = b_attn[0];
    const int k4 = lane * 4;
    const float4 wc4 = *(const float4*)(w_c + k4);
    const float4 vv4 = *(const float4*)(v_vec + k4);
    const int kg = tid & 255, grp = tid >> 8;  // 4 groups of 256
    float covl = 0.f;

    if (tid < CS) cov_s[tid] = 0.f;
    if (tid < CH) h_cur[tid] = hidden[b * CH + tid];
    __syncthreads();
    {  // hWs init
      float acc = 0.f;
#pragma unroll 8
      for (int j = grp * 64; j < grp * 64 + 64; ++j)
        acc += h_cur[j] * bf2f(W_sT16[j * CH + kg]);
      pctx[grp * CH + kg] = acc;
    }
    __syncthreads();
    if (tid < CH)
      hws_s[tid] = pctx[tid] + pctx[CH + tid] + pctx[2 * CH + tid] +
                   pctx[3 * CH + tid];
    __syncthreads();

    for (int t = 0; t < CTM1; ++t) {
      // ---- phase A: coverage, scores, softmax, ctx, publish ctx ----
      if (t > 0) {
        if (tid < CS) {
          float a = a_s[tid], cv = cov_s[tid];
          covl += fminf(a, cv);
          cov_s[tid] = cv + a;
        }
        __syncthreads();
      }
      float ps = 0.f;
      for (int s = wv; s < CS; s += 16) {
        float cv = cov_s[s];
        U64 wq = *(const U64*)(Wh_h16 + ((size_t)(b * CS + s)) * CH + k4);
        float p =
            ftanh(bf2f((unsigned short)wq) + hws_s[k4] + cv * wc4.x + ba) *
                vv4.x +
            ftanh(bf2f((unsigned short)(wq >> 16)) + hws_s[k4 + 1] +
                  cv * wc4.y + ba) *
                vv4.y +
            ftanh(bf2f((unsigned short)(wq >> 32)) + hws_s[k4 + 2] +
                  cv * wc4.z + ba) *
                vv4.z +
            ftanh(bf2f((unsigned short)(wq >> 48)) + hws_s[k4 + 3] +
                  cv * wc4.w + ba) *
                vv4.w;
        p = wave_sum(p);
        if (lane == 0) {
          float e = (s < len) ? __expf(p) : 0.f;  // |score| <~ 10: safe
          a_s[s] = e;
          ps += e;
        }
      }
      if (lane == 0) red[wv] = ps;
      __syncthreads();
      if (tid == 0) {
        float s2 = 0.f;
#pragma unroll
        for (int i = 0; i < 16; ++i) s2 += red[i];
        stat[0] = 1.f / s2;
      }
      __syncthreads();
      const float inv = stat[0];
      if (tid < CS) {
        float a = a_s[tid] * inv;
        a_s[tid] = a;
        attn16[((size_t)t * CB + b) * CS + tid] = f2bf(a);
      }
      __syncthreads();
      {  // ctx partials
        float pc = 0.f;
        const unsigned short* er =
            enc16 + ((size_t)(b * CS + grp * 100)) * CH + kg;
#pragma unroll 10
        for (int i = 0; i < 100; ++i)
          pc += a_s[grp * 100 + i] * bf2f(er[(size_t)i * CH]);
        pctx[grp * CH + kg] = pc;
      }
      __syncthreads();
      if (tid < CH)
        ctx_s[tid] = pctx[tid] + pctx[CH + tid] + pctx[2 * CH + tid] +
                     pctx[3 * CH + tid];
      __syncthreads();
      if (tid < 64) {  // publish ctx -> A64 ctx-half (UC)
        ast64(&A64[(size_t)t * 2048 + b * 128 + 64 + tid],
              pack4(ctx_s[4 * tid], ctx_s[4 * tid + 1], ctx_s[4 * tid + 2],
                    ctx_s[4 * tid + 3]));
      }
      VM0;
      __syncthreads();
      if (tid == 0) ast32(&xrdy[b * 16], (U32)(t + 1));
      // off-path while gates work: emb for p_gen
      if (tid < CE)
        emb_s[tid] = embedding[(size_t)tgt[b * CT + t] * CE + tid];
      // ---- wait gates (h slices ready) ----
      if (wv == 0) {
        int gg = 0;
        while (gg < (1 << 22)) {
          U32 v = (lane < NGT) ? ald32(&grdy[lane * 16]) : (U32)(t + 1);
          if (__all(v >= (U32)(t + 1))) break;
          __builtin_amdgcn_s_sleep(1);
          ++gg;
        }
      }
      __syncthreads();
      // ---- phase C: stage h (fp32, cached; per-t address), hWs, p_gen ----
      if (tid < CH) h_cur[tid] = HexF[((size_t)t * CB + b) * CH + tid];
      __syncthreads();
      {
        float acc = 0.f;
#pragma unroll 8
        for (int j = grp * 64; j < grp * 64 + 64; ++j)
          acc += h_cur[j] * bf2f(W_sT16[j * CH + kg]);
        pctx[grp * CH + kg] = acc;
      }
      __syncthreads();
      if (tid < CH)
        hws_s[tid] = pctx[tid] + pctx[CH + tid] + pctx[2 * CH + tid] +
                     pctx[3 * CH + tid];
      {
        float z = 0.f;
        if (tid < CH)
          z = h_cur[tid] * W_pg[tid] + ctx_s[tid] * W_pg[CH + tid];
        if (tid < CE) z += emb_s[tid] * W_pg[2 * CH + tid];
        z = wave_sum(z);
        if (lane == 0) red[wv] = z;
        __syncthreads();
        if (tid == 0) {
          float s2 = 0.f;
#pragma unroll
          for (int i = 0; i < 16; ++i) s2 += red[i];
          p_gen_g[t * CB + b] = sigm(s2 + b_pg[0]);
        }
      }
      __syncthreads();
    }
    // tail: covloss t=49 + totals + hT
    if (tid < CS) covl += fminf(a_s[tid], cov_s[tid]);
    covl = wave_sum(covl);
    if (lane == 0) red[wv] = covl;
    __syncthreads();
    if (tid == 0) {
      float s2 = 0.f;
#pragma unroll
      for (int i = 0; i < 16; ++i) s2 += red[i];
      covloss_b[b] = s2;
    }
    if (tid < CH) {
      const size_t D0 = (size_t)CB * CTM1 * CEXT;
      dout[D0 + b * CH + tid] = h_cur[tid];
    }
  } else if (bid < NST + NGT) {
    // ========== GATE BLOCKS: units u in [g*16,+16), all batches ==========
    const int g = bid - NST;
    const int nn = lane & 15, gq = lane >> 4;
    U64* xg64 = sh_big;               // [16][162] u64 = [16][648] shorts
    short* xg_s = (short*)sh_big;
    const short8* x8 = (const short8*)sh_big;
    // per-thread cell state (tid<256): b=tid>>4, j=tid&15, u=g*16+j
    const int cb = tid >> 4, cj = tid & 15, cu = g * 16 + (tid & 15);
    float c_reg = 0.f, bi0 = 0.f, bi1 = 0.f, bi2 = 0.f, bi3 = 0.f;
    if (tid < 256) {
      c_reg = cell[cb * CH + cu];
      bi0 = b_ih[cu] + b_hh[cu];
      bi1 = b_ih[CH + cu] + b_hh[CH + cu];
      bi2 = b_ih[2 * CH + cu] + b_hh[2 * CH + cu];
      bi3 = b_ih[3 * CH + cu] + b_hh[3 * CH + cu];
    }
    for (int t = 0; t < CTM1; ++t) {
      // -- precompute window (overlaps state phase A) --
      if (t > 0 && wv == 0) {  // all gate h-slices of t-1 visible?
        int gg = 0;
        while (gg < (1 << 22)) {
          U32 v = (lane < NGT) ? ald32(&grdy[lane * 16]) : (U32)t;
          if (__all(v >= (U32)t)) break;
          __builtin_amdgcn_s_sleep(1);
          ++gg;
        }
      }
      if (tid < CB) sh_tok[tid] = tgt[tid * CT + t];
      __syncthreads();
      // stage emb(t) + h(t-1) into xg
      for (int idx = tid; idx < CB * CE; idx += 1024) {
        int bb = idx >> 7, k = idx & 127;
        xg_s[bb * 648 + k] = (short)f2bf(embedding[(size_t)sh_tok[bb] * CE + k]);
      }
      if (t == 0) {
        for (int idx = tid; idx < CB * CH; idx += 1024) {
          int bb = idx >> 8, k = idx & 255;
          xg_s[bb * 648 + 384 + k] = (short)f2bf(hidden[bb * CH + k]);
        }
      } else {
        if (tid < 1024) {
          int bb = tid >> 6, i = tid & 63;
          xg64[bb * 162 + 96 + i] = A64[(size_t)(t - 1) * 2048 + bb * 128 + i];
        }
      }
      __syncthreads();
      f32x4 acc = {0.f, 0.f, 0.f, 0.f};
      if (wv < 4) {  // emb part kt 0..3, h part kt 12..19
        const int ncol = wv * 256 + g * 16 + nn;
        const short8* bp = (const short8*)Wcat + (size_t)ncol * 80;
#pragma unroll
        for (int kt = 0; kt < 4; ++kt)
          acc = __builtin_amdgcn_mfma_f32_16x16x32_bf16(
              x8[nn * 81 + kt * 4 + gq], bp[kt * 4 + gq], acc, 0, 0, 0);
#pragma unroll
        for (int kt = 12; kt < 20; ++kt)
          acc = __builtin_amdgcn_mfma_f32_16x16x32_bf16(
              x8[nn * 81 + kt * 4 + gq], bp[kt * 4 + gq], acc, 0, 0, 0);
      }
      // -- wait ctx --
      if (wv == 0) {
        int gg = 0;
        while (gg < (1 << 22)) {
          U32 v = (lane < NST) ? ald32(&xrdy[lane * 16]) : (U32)(t + 1);
          if (__all(v >= (U32)(t + 1))) break;
          __builtin_amdgcn_s_sleep(1);
          ++gg;
        }
      }
      __syncthreads();
      if (tid < 1024) {  // stage ctx (cached; per-t address)
        int bb = tid >> 6, i = tid & 63;
        xg64[bb * 162 + 32 + i] = A64[(size_t)t * 2048 + bb * 128 + 64 + i];
      }
      __syncthreads();
      if (wv < 4) {  // ctx part kt 4..11
        const int ncol = wv * 256 + g * 16 + nn;
        const short8* bp = (const short8*)Wcat + (size_t)ncol * 80;
#pragma unroll
        for (int kt = 4; kt < 12; ++kt)
          acc = __builtin_amdgcn_mfma_f32_16x16x32_bf16(
              x8[nn * 81 + kt * 4 + gq], bp[kt * 4 + gq], acc, 0, 0, 0);
#pragma unroll
        for (int r = 0; r < 4; ++r) gsl[wv][gq * 4 + r][nn] = acc[r];
      }
      __syncthreads();
      if (tid < 256) {  // cell update + publish h slice
        float gi = gsl[0][cb][cj] + bi0;
        float gf = gsl[1][cb][cj] + bi1;
        float gg2 = gsl[2][cb][cj] + bi2;
        float go = gsl[3][cb][cj] + bi3;
        float cn = sigm(gf) * c_reg + sigm(gi) * ftanh(gg2);
        c_reg = cn;
        float hn = sigm(go) * ftanh(cn);
        ast32((U32*)&HexF[((size_t)t * CB + cb) * CH + cu],
              __float_as_uint(hn));
        float h1 = __shfl_down(hn, 1);
        float h2 = __shfl_down(hn, 2);
        float h3 = __shfl_down(hn, 3);
        if (!(cj & 3))  // A64 h-half bf16 (u64 index u/4)
          ast64(&A64[(size_t)t * 2048 + cb * 128 + (cu >> 2)],
                pack4(hn, h1, h2, h3));
      }
      VM0;
      __syncthreads();
      if (tid == 0) ast32(&grdy[g * 16], (U32)(t + 1));
    }
    // tail: cT slice
    if (tid < 256) {
      const size_t D0 = (size_t)CB * CTM1 * CEXT;
      dout[D0 + CB * CH + cb * CH + cu] = c_reg;
    }
  } else if (bid == NST + NGT) {
    // ===================== AGGREGATOR (1 block) ==========================
    for (int t = 0; t < CTM1; ++t) {
      if (wv == 0) {
        int gg = 0;
        while (gg < (1 << 22)) {
          U32 v = (lane < NGT) ? ald32(&grdy[lane * 16]) : (U32)(t + 1);
          if (__all(v >= (U32)(t + 1))) break;
          __builtin_amdgcn_s_sleep(4);
          ++gg;
        }
      }
      __syncthreads();
      if (tid < 64) ast32(&release[tid * 16], (U32)(t + 1));
      __syncthreads();
    }
  } else {
    // ============ VOCAB WORKERS (223 blocks, 16 waves, 4 tiles) ==========
    const int vb = bid - NST - NGT - 1;
    const int rep = vb & 63;
    const int nn = lane & 15, g = lane >> 4;
    const int t4 = (wv >> 2) * NWK + vb;
    const int v = t4 * 64 + (wv & 3) * 16 + nn;
    const bool live = (t4 < NTILE) && (v < CV);
    const int vc = live ? v : CV - 1;
    U64* a64l = sh_big;  // [16][130] u64
    const short8* lds8 = (const short8*)sh_big;
    const short8* bp = (const short8*)Wb + (size_t)vc * 64;
    const float bo = live ? b_out[v] : 0.f;
    for (int t = 0; t < CTM1; ++t) {
      if (tid == 0) {
        int gg = 0;
        while (ald32(&release[rep * 16]) < (U32)(t + 1) && ++gg < (1 << 18))
          __builtin_amdgcn_s_sleep(32);
      }
      __syncthreads();
      {  // stage A slab cached
        const U64* src = A64 + (size_t)t * 2048;
#pragma unroll
        for (int i = 0; i < 2; ++i) {
          int idx = tid + i * 1024;
          int row = idx >> 7, col = idx & 127;
          a64l[row * 130 + col] = src[idx];
        }
      }
      __syncthreads();
      short8 af[16];
#pragma unroll
      for (int kt = 0; kt < 16; ++kt) af[kt] = lds8[nn * 65 + kt * 4 + g];
      f32x4 acc = {0.f, 0.f, 0.f, 0.f};
#pragma unroll
      for (int kt = 0; kt < 16; ++kt)
        acc = __builtin_amdgcn_mfma_f32_16x16x32_bf16(af[kt], bp[kt * 4 + g],
                                                      acc, 0, 0, 0);
      float ev[4];
#pragma unroll
      for (int r = 0; r < 4; ++r) {
        float e = live ? __expf(acc[r] + bo) : 0.f;
        if (live) dout[((size_t)((g * 4 + r) * CTM1 + t)) * CEXT + v] = e;
#pragma unroll
        for (int o = 1; o < 16; o <<= 1) e += __shfl_xor(e, o);
        ev[r] = e;
      }
      if (nn == 0) {
#pragma unroll
        for (int r = 0; r < 4; ++r) prs[wv][g * 4 + r] = ev[r];
      }
      __syncthreads();
      if (tid < 16) {
        float s = 0.f;
#pragma unroll
        for (int w = 0; w < 16; ++w) s += prs[w][tid];
        atomicAdd(&part[((size_t)t * CB + tid) * 64 + rep], s);
      }
      __syncthreads();
    }
  }
}

// ---------------------------------------------------------------------------
// POST 1: per (b,t) row: reduce 64 rowsum partials, normalize + zero pads.
// ---------------------------------------------------------------------------
__global__ __launch_bounds__(256) void post_norm(
    const float* __restrict__ part, const float* __restrict__ p_gen_g,
    float* __restrict__ dout) {
  const int R = blockIdx.x;
  const int b = R / CTM1, t = R % CTM1;
  const int tid = threadIdx.x;
  __shared__ float stat;
  float s = (tid < 64) ? part[((size_t)t * CB + b) * 64 + tid] : 0.f;
  s = wave_sum(s);
  if (tid == 0) stat = p_gen_g[t * CB + b] / s;
  __syncthreads();
  float inv = stat;
  float* drow = dout + (size_t)R * CEXT;
  for (int v = tid; v < CEXT; v += 256)
    drow[v] = (v < CV) ? drow[v] * inv : 0.f;
}

// ---------------------------------------------------------------------------
// POST 2: copy-dist scatter for all t + coverage_loss. grid = 16.
// ---------------------------------------------------------------------------
__global__ __launch_bounds__(256) void post_tail(
    const unsigned short* __restrict__ attn16,
    const float* __restrict__ p_gen_g, const int* __restrict__ copy_idx,
    const float* __restrict__ covloss_b, float* __restrict__ dout) {
  const int b = blockIdx.x, tid = threadIdx.x;
  for (int t = 0; t < CTM1; ++t) {
    float pg1 = 1.f - p_gen_g[t * CB + b];
    const unsigned short* ar = attn16 + ((size_t)t * CB + b) * CS;
    float* drow = dout + ((size_t)(b * CTM1 + t)) * CEXT;
    for (int s = tid; s < CS; s += 256)
      atomicAdd(drow + copy_idx[b * CS + s], pg1 * bf2f(ar[s]));
  }
  if (b == 0 && tid == 0) {
    const size_t D0 = (size_t)CB * CTM1 * CEXT;
    float s = 0.f;
    for (int i = 0; i < CB; ++i) s += covloss_b[i];
    dout[D0 + 2 * CB * CH] = s / (float)(CTM1 * CB);
  }
}

// ---------------------------------------------------------------------------
extern "C" void kernel_launch(void* const* d_in, const int* in_sizes, int n_in,
                              void* d_out, int out_size, void* d_ws,
                              size_t ws_size, hipStream_t stream) {
  const int* tgt = (const int*)d_in[0];
  const float* hidden = (const float*)d_in[1];
  const float* cell = (const float*)d_in[2];
  const float* enc = (const float*)d_in[3];
  const int* src_lens = (const int*)d_in[4];
  const int* src_ids = (const int*)d_in[5];
  const int* src_oov = (const int*)d_in[6];
  const float* embedding = (const float*)d_in[7];
  const float* W_h = (const float*)d_in[8];
  const float* W_s = (const float*)d_in[9];
  const float* w_c = (const float*)d_in[10];
  const float* v_vec = (const float*)d_in[11];
  const float* b_attn = (const float*)d_in[12];
  const float* W_ih = (const float*)d_in[13];
  const float* W_hh = (const float*)d_in[14];
  const float* b_ih = (const float*)d_in[15];
  const float* b_hh = (const float*)d_in[16];
  const float* W_pg = (const float*)d_in[17];
  const float* b_pg = (const float*)d_in[18];
  const float* W_out = (const float*)d_in[19];
  const float* b_out = (const float*)d_in[20];
  float* dout = (float*)d_out;

  // workspace layout (word count before u64 region is even)
  float* ws = (float*)d_ws;
  float* W_hT = ws;                                  // 65,536 f
  float* p_gen_g = W_hT + CH * CH;                   // 800 f
  float* part = p_gen_g + CTM1 * CB;                 // 51,200 f
  float* covloss_b = part + CTM1 * CB * 64;          // 16 f
  float* HexF = covloss_b + 16;                      // 204,800 f
  int* copy_idx = (int*)(HexF + (size_t)CTM1 * CB * CH);  // 6,400 i
  U32* ctrl = (U32*)(copy_idx + CB * CS);            // 2,048 u32
  U64* A64 = (U64*)(ctrl + 2048);                    // 102,400 u64
  unsigned short* attn16 =
      (unsigned short*)(A64 + (size_t)CTM1 * 2048);  // 320,000 sh
  unsigned short* Wh_h16 = attn16 + (size_t)CTM1 * CB * CS;  // 1,638,400 sh
  unsigned short* enc16 = Wh_h16 + (size_t)CB * CS * CH;     // 1,638,400 sh
  unsigned short* W_sT16 = enc16 + (size_t)CB * CS * CH;     // 65,536 sh
  unsigned short* Wcat = W_sT16 + CH * CH;           // 655,360 sh
  unsigned short* Wb = Wcat + (size_t)(4 * CH) * CX; // 25,600,000 sh

  z_init<<<64, 256, 0, stream>>>(ctrl, part);
  pw_convert<<<(CV * 2 * CH) / (256 * 8), 256, 0, stream>>>(W_out, Wb);
  pw_cat<<<((4 * CH) * CX / 8) / 256, 256, 0, stream>>>(W_ih, W_hh, Wcat);
  pw_t256<<<CH, CH, 0, stream>>>(W_h, W_hT);
  pw_t256_bf16<<<CH, CH, 0, stream>>>(W_s, W_sT16);
  pw_cvt16<<<(CB * CS * CH) / (256 * 8), 256, 0, stream>>>(enc, enc16);
  p0_precompute<<<CB * CS / 8, 256, 0, stream>>>(enc, W_hT, src_ids, src_oov,
                                                 Wh_h16, copy_idx);

  void* kargs[] = {
      (void*)&tgt,      (void*)&hidden,    (void*)&cell,    (void*)&src_lens,
      (void*)&embedding,(void*)&w_c,       (void*)&v_vec,   (void*)&b_attn,
      (void*)&b_ih,     (void*)&b_hh,      (void*)&W_pg,    (void*)&b_pg,
      (void*)&b_out,    (void*)&Wh_h16,    (void*)&enc16,   (void*)&W_sT16,
      (void*)&Wcat,     (void*)&Wb,        (void*)&A64,     (void*)&HexF,
      (void*)&attn16,   (void*)&p_gen_g,   (void*)&part,    (void*)&covloss_b,
      (void*)&ctrl,     (void*)&dout};
  hipError_t e = hipLaunchCooperativeKernel((const void*)mega, dim3(NBLK),
                                            dim3(1024), kargs, 0, stream);
  if (e != hipSuccess) {
    hipLaunchKernelGGL(mega, dim3(NBLK), dim3(1024), 0, stream, tgt, hidden,
                       cell, src_lens, embedding, w_c, v_vec, b_attn, b_ih,
                       b_hh, W_pg, b_pg, b_out, Wh_h16, enc16, W_sT16, Wcat,
                       Wb, A64, HexF, attn16, p_gen_g, part, covloss_b, ctrl,
                       dout);
  }
  post_norm<<<CB * CTM1, 256, 0, stream>>>(part, p_gen_g, dout);
  post_tail<<<CB, 256, 0, stream>>>(attn16, p_gen_g, copy_idx, covloss_b,
                                    dout);
}